// Round 1
// baseline (695.048 us; speedup 1.0000x reference)
//
#include <hip/hip_runtime.h>

#define B_   20
#define T_   20
#define RN   20
#define D_   4096
#define O_   16
#define E_   512
#define H_   8
#define DH   64
#define TM_  1900
#define NKV  420          // per-batch kv rows: 400 region + 20 mem
#define MROWS (B_*NKV)    // 8400
#define MPAD 8448         // 66 * 128
#define NW   1536         // Wk|Wv|W1 output channels
#define NSIM 1920         // 15 * 128 (TM padded)
#define MSIM 512          // 4 * 128 (B*T padded)
#define CAP  256

using f32x4  = __attribute__((ext_vector_type(4))) float;
using bf16x8 = __attribute__((ext_vector_type(8))) __bf16;

__device__ __forceinline__ unsigned short f2bf(float f){
  unsigned u = __float_as_uint(f);
  u += 0x7fffu + ((u >> 16) & 1u);
  return (unsigned short)(u >> 16);
}

__device__ __forceinline__ void st_bf4(unsigned short* dst, float4 v){
  ushort4 o = make_ushort4(f2bf(v.x), f2bf(v.y), f2bf(v.z), f2bf(v.w));
  *(ushort4*)dst = o;
}

__device__ __forceinline__ float bsum256(float v, float* sh){
  int t = threadIdx.x;
  for (int o = 32; o; o >>= 1) v += __shfl_down(v, o, 64);
  __syncthreads();
  if ((t & 63) == 0) sh[t >> 6] = v;
  __syncthreads();
  return sh[0] + sh[1] + sh[2] + sh[3];
}

__device__ __forceinline__ float bmax256(float v, float* sh){
  int t = threadIdx.x;
  for (int o = 32; o; o >>= 1) v = fmaxf(v, __shfl_down(v, o, 64));
  __syncthreads();
  if ((t & 63) == 0) sh[t >> 6] = v;
  __syncthreads();
  return fmaxf(fmaxf(sh[0], sh[1]), fmaxf(sh[2], sh[3]));
}

__device__ __forceinline__ void gld16(const void* g, void* l){
  __builtin_amdgcn_global_load_lds(
      (const __attribute__((address_space(1))) unsigned int*)g,
      (__attribute__((address_space(3))) unsigned int*)l, 16, 0, 0);
}

// ---------- weight transpose+convert: W_all[n][k] = bf16(src[k][n]) ----------
__global__ __launch_bounds__(256) void k_wt(const float* __restrict__ Wk, const float* __restrict__ Wv,
                                            const float* __restrict__ W1, unsigned short* __restrict__ Wall){
  __shared__ float tile[32][33];
  int kb = blockIdx.x * 32, nb = blockIdx.y * 32;
  const float* src; int nc0;
  if (nb < 512)      { src = Wk; nc0 = nb; }
  else if (nb < 1024){ src = Wv; nc0 = nb - 512; }
  else               { src = W1; nc0 = nb - 1024; }
  int tx = threadIdx.x, ty = threadIdx.y;
  for (int j = 0; j < 4; ++j){
    int k = kb + ty + j*8;
    tile[ty + j*8][tx] = src[(size_t)k*E_ + nc0 + tx];
  }
  __syncthreads();
  for (int j = 0; j < 4; ++j){
    int n = nb + ty + j*8;
    int k = kb + tx;
    Wall[(size_t)n*D_ + k] = f2bf(tile[tx][ty + j*8]);
  }
}

// ---------- per-row 1/norm of features ----------
__global__ __launch_bounds__(256) void k_rnorm(const float* __restrict__ F, float* __restrict__ rinv){
  int r = blockIdx.x, t = threadIdx.x;
  const float4* p = (const float4*)(F + (size_t)r*D_);
  float s = 0.f;
  for (int i = 0; i < 4; ++i){ float4 v = p[i*256 + t]; s += v.x*v.x + v.y*v.y + v.z*v.z + v.w*v.w; }
  __shared__ float sh[4];
  s = bsum256(s, sh);
  if (t == 0) rinv[r] = 1.f / fmaxf(sqrtf(s), 1e-12f);
}

// ---------- normalize features -> A_kv(bf16), region max -> rmaxr + rmsum ----------
__global__ __launch_bounds__(256) void k_normmax(const float* __restrict__ F, const float* __restrict__ rinv,
                                                 unsigned short* __restrict__ A, float* __restrict__ rmaxr,
                                                 float* __restrict__ rmsum){
  int bt = blockIdx.x, ch = blockIdx.y, t = threadIdx.x;
  int b = bt / T_, tt = bt % T_;
  size_t col = (size_t)ch*1024 + t*4;
  const float* fb = F + (size_t)bt*RN*D_ + col;
  unsigned short* ab = A + ((size_t)b*NKV + (size_t)tt*RN)*D_ + col;
  float4 mx = make_float4(-1e30f,-1e30f,-1e30f,-1e30f);
  for (int r = 0; r < RN; ++r){
    float4 v = *(const float4*)(fb + (size_t)r*D_);
    float ri = rinv[bt*RN + r];
    v.x *= ri; v.y *= ri; v.z *= ri; v.w *= ri;
    st_bf4(ab + (size_t)r*D_, v);
    mx.x = fmaxf(mx.x, v.x); mx.y = fmaxf(mx.y, v.y);
    mx.z = fmaxf(mx.z, v.z); mx.w = fmaxf(mx.w, v.w);
  }
  *(float4*)(rmaxr + (size_t)bt*D_ + col) = mx;
  float s = mx.x*mx.x + mx.y*mx.y + mx.z*mx.z + mx.w*mx.w;
  __shared__ float sh[4];
  s = bsum256(s, sh);
  if (t == 0) atomicAdd(&rmsum[bt], s);
}

// ---------- generic: dst(bf16 row) = src * (1/max(sqrt(s2),eps)) ----------
__global__ __launch_bounds__(256) void k_normbf(const float* __restrict__ src, const float* __restrict__ s2,
                                                unsigned short* __restrict__ dst){
  int r = blockIdx.x, t = threadIdx.x;
  float inv = 1.f / fmaxf(sqrtf(s2[r]), 1e-12f);
  for (int i = 0; i < 4; ++i){
    size_t off = (size_t)r*D_ + i*1024 + t*4;
    float4 v = *(const float4*)(src + off);
    v.x *= inv; v.y *= inv; v.z *= inv; v.w *= inv;
    st_bf4(dst + off, v);
  }
}

// ---------- temporal_mem frame max-pool -> umax + msum ----------
__global__ __launch_bounds__(256) void k_umax(const float* __restrict__ TMm, float* __restrict__ umax,
                                              float* __restrict__ msum){
  int m = blockIdx.x, ch = blockIdx.y, t = threadIdx.x;
  size_t col = (size_t)ch*1024 + t*4;
  const float* base = TMm + (size_t)m*T_*D_ + col;
  float4 mx = make_float4(-1e30f,-1e30f,-1e30f,-1e30f);
  for (int f = 0; f < T_; ++f){
    float4 v = *(const float4*)(base + (size_t)f*D_);
    mx.x = fmaxf(mx.x, v.x); mx.y = fmaxf(mx.y, v.y);
    mx.z = fmaxf(mx.z, v.z); mx.w = fmaxf(mx.w, v.w);
  }
  *(float4*)(umax + (size_t)m*D_ + col) = mx;
  float s = mx.x*mx.x + mx.y*mx.y + mx.z*mx.z + mx.w*mx.w;
  __shared__ float sh[4];
  s = bsum256(s, sh);
  if (t == 0) atomicAdd(&msum[m], s);
}

// ---------- 128x128 bf16 MFMA GEMM: C[M][N] = A[M][K] * Bw[N][K]^T, K=4096 ----------
__global__ __launch_bounds__(256, 2) void k_gemm(const unsigned short* __restrict__ A,
                                                 const unsigned short* __restrict__ Bw,
                                                 float* __restrict__ C,
                                                 int nNt, int ldc, int doswz, int nwg){
  __shared__ char lds[32768];
  int bid = blockIdx.x;
  if (doswz){ int q = nwg >> 3; bid = (bid & 7)*q + (bid >> 3); }
  int mt = bid / nNt, nt = bid % nNt;
  int tid = threadIdx.x, wv = tid >> 6, l = tid & 63;
  int wr = (wv >> 1) * 64, wc = (wv & 1) * 64;
  const char* Ab = (const char*)A + (size_t)mt*128*(size_t)(D_*2);
  const char* Bb = (const char*)Bw + (size_t)nt*128*(size_t)(D_*2);
  f32x4 acc[4][4];
#pragma unroll
  for (int m = 0; m < 4; ++m)
#pragma unroll
    for (int n = 0; n < 4; ++n) acc[m][n] = (f32x4){0.f,0.f,0.f,0.f};
  for (int kt = 0; kt < D_/64; ++kt){
    int ktoff = kt*128;
#pragma unroll
    for (int i = 0; i < 4; ++i){
      int idx = i*256 + tid;
      int row = idx >> 3, u = idx & 7;
      int ul = u ^ (row & 7);   // pre-swizzled global source (st-style XOR, G21)
      gld16(Ab + (size_t)row*(D_*2) + ktoff + ul*16, lds + i*4096 + wv*1024);
      gld16(Bb + (size_t)row*(D_*2) + ktoff + ul*16, lds + 16384 + i*4096 + wv*1024);
    }
    __syncthreads();
#pragma unroll
    for (int kk = 0; kk < 2; ++kk){
      bf16x8 av[4], bv[4];
#pragma unroll
      for (int m = 0; m < 4; ++m){
        int row = wr + m*16 + (l & 15);
        int u = (kk*4 + (l >> 4)) ^ (row & 7);
        av[m] = *(const bf16x8*)(lds + row*128 + u*16);
      }
#pragma unroll
      for (int n = 0; n < 4; ++n){
        int row = wc + n*16 + (l & 15);
        int u = (kk*4 + (l >> 4)) ^ (row & 7);
        bv[n] = *(const bf16x8*)(lds + 16384 + row*128 + u*16);
      }
#pragma unroll
      for (int m = 0; m < 4; ++m)
#pragma unroll
        for (int n = 0; n < 4; ++n)
          acc[m][n] = __builtin_amdgcn_mfma_f32_16x16x32_bf16(av[m], bv[n], acc[m][n], 0, 0, 0);
    }
    __syncthreads();
  }
  int rq = (l >> 4) * 4, cq = l & 15;
  size_t crow0 = (size_t)mt*128 + wr, ccol0 = (size_t)nt*128 + wc;
#pragma unroll
  for (int m = 0; m < 4; ++m)
#pragma unroll
    for (int n = 0; n < 4; ++n){
      size_t r0 = crow0 + m*16 + rq, c0 = ccol0 + n*16 + cq;
#pragma unroll
      for (int j = 0; j < 4; ++j)
        C[(r0 + j)*ldc + c0] = acc[m][n][j];
    }
}

// ---------- kNN candidate collect (bf16 sims, margin prune) ----------
__global__ __launch_bounds__(256) void k_cand(const float* __restrict__ simc, int* __restrict__ cand,
                                              int* __restrict__ ccnt){
  int bt = blockIdx.x, t = threadIdx.x;
  const float* row = simc + (size_t)bt*NSIM;
  __shared__ float sh[4];
  __shared__ int cnt;
  float mx = -1e30f;
  for (int m = t; m < TM_; m += 256) mx = fmaxf(mx, row[m]);
  mx = bmax256(mx, sh);
  if (t == 0) cnt = 0;
  __syncthreads();
  float thr = mx - 2.5e-4f;
  for (int m = t; m < TM_; m += 256){
    if (row[m] >= thr){
      int p = atomicAdd(&cnt, 1);
      if (p < CAP) cand[bt*CAP + p] = m;
    }
  }
  __syncthreads();
  if (t == 0) ccnt[bt] = cnt < CAP ? cnt : CAP;
}

// ---------- fp32 rescore of candidates -> exact argmax ----------
__global__ __launch_bounds__(256) void k_rescore(const float* __restrict__ rmaxr, const float* __restrict__ rmsum,
                                                 const float* __restrict__ umax, const float* __restrict__ msum,
                                                 const int* __restrict__ cand, const int* __restrict__ ccnt,
                                                 int* __restrict__ idxo){
  int bt = blockIdx.x, t = threadIdx.x;
  __shared__ float sh[4];
  int cnt = ccnt[bt];
  float rinvv = 1.f / fmaxf(sqrtf(rmsum[bt]), 1e-12f);
  const float* a = rmaxr + (size_t)bt*D_;
  float best = -1e30f; int bestm = 0x7fffffff;
  for (int ci = 0; ci < cnt; ++ci){
    int m = cand[bt*CAP + ci];
    const float* wrow = umax + (size_t)m*D_;
    float p = 0.f;
    for (int i = t*4; i < D_; i += 1024){
      float4 av = *(const float4*)(a + i);
      float4 wv = *(const float4*)(wrow + i);
      p += av.x*wv.x + av.y*wv.y + av.z*wv.z + av.w*wv.w;
    }
    p = bsum256(p, sh);
    float sim = p * rinvv * (1.f / fmaxf(sqrtf(msum[m]), 1e-12f));
    if (sim > best || (sim == best && m < bestm)){ best = sim; bestm = m; }
  }
  if (t == 0) idxo[bt] = bestm;
}

// ---------- gather retrieved memory rows into A_kv (bf16) ----------
__global__ __launch_bounds__(256) void k_memfeat(const float* __restrict__ umax, const int* __restrict__ idx,
                                                 unsigned short* __restrict__ A){
  int bt = blockIdx.x, t = threadIdx.x;
  int b = bt / T_, tt = bt % T_;
  int m = idx[bt];
  unsigned short* dst = A + ((size_t)b*NKV + 400 + tt)*D_;
  const float* src = umax + (size_t)m*D_;
  for (int i = 0; i < 4; ++i){
    size_t off = (size_t)i*1024 + t*4;
    float4 v = *(const float4*)(src + off);
    st_bf4(dst + off, v);
  }
}

// ---------- q = (onehot@entity_W + entity_b) @ Wq ----------
__global__ __launch_bounds__(256) void k_q(const int* __restrict__ labels, const float* __restrict__ entW,
                                           const float* __restrict__ entB, const float* __restrict__ Wq,
                                           float* __restrict__ q){
  int bo = blockIdx.x, t = threadIdx.x;
  __shared__ float qe[E_];
  int lab = labels[bo];
  float sel = (lab != 0) ? 1.f : 0.f;
  qe[t]       = sel * entW[(size_t)lab*E_ + t]       + entB[t];
  qe[t + 256] = sel * entW[(size_t)lab*E_ + t + 256] + entB[t + 256];
  __syncthreads();
  float a0 = 0.f, a1 = 0.f;
  for (int ep = 0; ep < E_; ++ep){
    float r = qe[ep];
    a0 += r * Wq[(size_t)ep*E_ + t];
    a1 += r * Wq[(size_t)ep*E_ + t + 256];
  }
  q[(size_t)bo*E_ + t] = a0;
  q[(size_t)bo*E_ + t + 256] = a1;
}

// ---------- attention per (b,h): scores -> softmax -> attn@v ----------
__global__ __launch_bounds__(256) void k_attn(const float* __restrict__ q, const float* __restrict__ c2,
                                              float* __restrict__ fpre){
  int bh = blockIdx.x; int b = bh >> 3, h = bh & 7;
  int t = threadIdx.x, w = t >> 6, l = t & 63;
  __shared__ float qhp[O_][DH + 1];
  __shared__ float kb[105][DH + 1];
  __shared__ float sc[O_][NKV];
  for (int i = t; i < O_*DH; i += 256){
    int o = i >> 6, d = i & 63;
    qhp[o][d] = q[((size_t)(b*O_ + o))*E_ + h*DH + d] * 0.125f;
  }
  __syncthreads();
  for (int c = 0; c < 4; ++c){
    for (int i = t; i < 105*DH; i += 256){
      int j = i >> 6, d = i & 63;
      kb[j][d] = c2[((size_t)(b*NKV + c*105 + j))*NW + h*DH + d];
    }
    __syncthreads();
    for (int i = t; i < O_*105; i += 256){
      int o = i / 105, j = i % 105;
      float acc = 0.f;
      for (int d = 0; d < DH; ++d) acc += qhp[o][d] * kb[j][d];
      sc[o][c*105 + j] = acc;
    }
    __syncthreads();
  }
  for (int oi = 0; oi < 4; ++oi){
    int o = w + oi*4;
    float mx = -1e30f;
    for (int n = l; n < NKV; n += 64) mx = fmaxf(mx, sc[o][n]);
    for (int off = 32; off; off >>= 1) mx = fmaxf(mx, __shfl_xor(mx, off, 64));
    float sum = 0.f;
    for (int n = l; n < NKV; n += 64){ float e = expf(sc[o][n] - mx); sc[o][n] = e; sum += e; }
    for (int off = 32; off; off >>= 1) sum += __shfl_xor(sum, off, 64);
    float inv = 1.f / sum;
    for (int n = l; n < NKV; n += 64) sc[o][n] *= inv;
  }
  __syncthreads();
  for (int og = 0; og < 4; ++og){
    int o = og*4 + w;
    float acc = 0.f;
    for (int n = 0; n < NKV; ++n)
      acc += sc[o][n] * c2[((size_t)(b*NKV + n))*NW + E_ + h*DH + l];
    fpre[((size_t)(b*O_ + o))*E_ + h*DH + l] = acc;
  }
}

// ---------- QR argmax/argmin per (b,o,t): QR = q.k/64 over full E ----------
__global__ __launch_bounds__(256) void k_hilo(const float* __restrict__ q, const float* __restrict__ c2,
                                              int* __restrict__ hi, int* __restrict__ lo){
  int bid = blockIdx.x;             // (b*O + o)*T + t
  int bo = bid / T_, tt = bid % T_;
  int b = bo / O_;
  int t = threadIdx.x, w = t >> 6, l = t & 63;
  __shared__ float qv[E_];
  __shared__ float qr[RN];
  for (int i = t; i < E_; i += 256) qv[i] = q[(size_t)bo*E_ + i];
  __syncthreads();
  for (int ri = 0; ri < 5; ++ri){
    int r = w*5 + ri;
    const float* kr = c2 + ((size_t)(b*NKV + tt*RN + r))*NW;
    float acc = 0.f;
    for (int e = l; e < E_; e += 64) acc += qv[e] * kr[e];
    for (int off = 32; off; off >>= 1) acc += __shfl_down(acc, off, 64);
    if (l == 0) qr[r] = acc;
  }
  __syncthreads();
  if (t == 0){
    float bh = qr[0], bl = qr[0]; int ih = 0, il = 0;
    for (int r = 1; r < RN; ++r){
      if (qr[r] > bh){ bh = qr[r]; ih = r; }
      if (qr[r] < bl){ bl = qr[r]; il = r; }
    }
    int rowbase = b*NKV + tt*RN;
    hi[bid] = rowbase + ih;
    lo[bid] = rowbase + il;
  }
}

// ---------- z = sigmoid(tanh(h1+b1)@W2 + b2) per kv row ----------
__global__ __launch_bounds__(256) void k_z(const float* __restrict__ c2, const float* __restrict__ b1,
                                           const float* __restrict__ W2, const float* __restrict__ b2,
                                           float* __restrict__ z){
  int row = blockIdx.x*4 + (threadIdx.x >> 6);
  int l = threadIdx.x & 63;
  const float* hrow = c2 + (size_t)row*NW + 1024;
  float acc = 0.f;
  for (int e = l; e < E_; e += 64) acc += tanhf(hrow[e] + b1[e]) * W2[e];
  for (int off = 32; off; off >>= 1) acc += __shfl_down(acc, off, 64);
  if (l == 0) z[row] = 1.f / (1.f + expf(-(acc + b2[0])));
}

// ---------- gce scalar (pre-scaled by beta) ----------
__global__ __launch_bounds__(256) void k_gce(const float* __restrict__ z, const int* __restrict__ hi,
                                             const int* __restrict__ lo, const int* __restrict__ labels,
                                             float* __restrict__ gout){
  __shared__ float vb[B_];
  __shared__ int cb[B_];
  int t = threadIdx.x;
  if (t < B_){ vb[t] = 0.f; cb[t] = 0; }
  __syncthreads();
  for (int p = t; p < B_*O_; p += 256){
    int b = p / O_;
    if (labels[p] != 0){
      float acc = 0.f;
      for (int tt = 0; tt < T_; ++tt){
        float shi = z[hi[p*T_ + tt]];
        float slo = z[lo[p*T_ + tt]];
        acc += (1.f - __powf(shi + 1e-7f, 0.7f)) / 0.7f;
        acc += (1.f - __powf(1.f - slo + 1e-7f, 0.7f)) / 0.7f;
      }
      atomicAdd(&vb[b], acc / (float)T_);
      atomicAdd(&cb[b], 1);
    }
  }
  __syncthreads();
  if (t == 0){
    float g = 0.f;
    for (int b = 0; b < B_; ++b) g += vb[b] / fmaxf((float)cb[b], 1.f);
    gout[0] = 0.5f * (g / (float)B_);
  }
}

// ---------- out = fpre @ Wo + beta*gce ----------
__global__ __launch_bounds__(256) void k_out(const float* __restrict__ fpre, const float* __restrict__ Wo,
                                             const float* __restrict__ gce, float* __restrict__ out){
  int bo = blockIdx.x, t = threadIdx.x;
  __shared__ float row[E_];
  row[t] = fpre[(size_t)bo*E_ + t];
  row[t + 256] = fpre[(size_t)bo*E_ + t + 256];
  __syncthreads();
  float g = gce[0];
  float a0 = 0.f, a1 = 0.f;
  for (int ep = 0; ep < E_; ++ep){
    float r = row[ep];
    a0 += r * Wo[(size_t)ep*E_ + t];
    a1 += r * Wo[(size_t)ep*E_ + t + 256];
  }
  out[(size_t)bo*E_ + t] = a0 + g;
  out[(size_t)bo*E_ + t + 256] = a1 + g;
}

extern "C" void kernel_launch(void* const* d_in, const int* in_sizes, int n_in,
                              void* d_out, int out_size, void* d_ws, size_t ws_size,
                              hipStream_t stream) {
  (void)in_sizes; (void)n_in; (void)out_size; (void)ws_size;
  const float* F    = (const float*)d_in[0];
  const int*   labels = (const int*)d_in[1];
  const float* TMm  = (const float*)d_in[2];
  const float* entW = (const float*)d_in[3];
  const float* entB = (const float*)d_in[4];
  const float* Wq   = (const float*)d_in[5];
  const float* Wk   = (const float*)d_in[6];
  const float* Wv   = (const float*)d_in[7];
  const float* Wo   = (const float*)d_in[8];
  const float* W1   = (const float*)d_in[9];
  const float* b1   = (const float*)d_in[10];
  const float* W2   = (const float*)d_in[11];
  const float* b2   = (const float*)d_in[12];
  float* out = (float*)d_out;

  size_t off = 0;
  char* wsb = (char*)d_ws;
  auto alloc = [&](size_t bytes) -> char* {
    char* p = wsb + off; off += (bytes + 255) & ~(size_t)255; return p;
  };
  unsigned short* A_kv = (unsigned short*)alloc((size_t)MPAD * D_ * 2);
  unsigned short* Wall = (unsigned short*)alloc((size_t)NW * D_ * 2);
  float* umax          = (float*)alloc((size_t)TM_ * D_ * 4);
  char*  c2reg         = alloc((size_t)MPAD * NW * 4);      // overlay region
  float* C2    = (float*)c2reg;
  unsigned short* wnorm = (unsigned short*)c2reg;                       // 15,728,640 B
  float* simc  = (float*)(c2reg + 15728640);                            //  3,932,160 B
  unsigned short* ubf = (unsigned short*)(c2reg + 19660800);            //  4,194,304 B
  float* rmaxr = (float*)(c2reg + 23855104);                            //  6,553,600 B
  float* qbuf  = (float*)alloc((size_t)B_ * O_ * E_ * 4);
  float* fpre  = (float*)alloc((size_t)B_ * O_ * E_ * 4);
  float* rinv  = (float*)alloc(8000 * 4);
  float* rmsum = (float*)alloc(400 * 4);
  float* msum  = (float*)alloc(TM_ * 4);
  int*   cand  = (int*)alloc(400 * CAP * 4);
  int*   ccnt  = (int*)alloc(400 * 4);
  int*   idxb  = (int*)alloc(400 * 4);
  int*   hib   = (int*)alloc(6400 * 4);
  int*   lob   = (int*)alloc(6400 * 4);
  float* zbuf  = (float*)alloc((size_t)MROWS * 4);
  float* gbuf  = (float*)alloc(256);

  // zero the atomic accumulators and pad rows (every call: deterministic)
  hipMemsetAsync(rmsum, 0, 400 * 4, stream);
  hipMemsetAsync(msum, 0, TM_ * 4, stream);
  hipMemsetAsync(ubf + (size_t)400 * D_, 0, (size_t)(MSIM - 400) * D_ * 2, stream);
  hipMemsetAsync(wnorm + (size_t)TM_ * D_, 0, (size_t)(NSIM - TM_) * D_ * 2, stream);
  hipMemsetAsync(A_kv + (size_t)MROWS * D_, 0, (size_t)(MPAD - MROWS) * D_ * 2, stream);

  // weights -> bf16 [N][K]
  k_wt<<<dim3(D_/32, NW/32), dim3(32, 8), 0, stream>>>(Wk, Wv, W1, Wall);
  // region features: l2norm, bf16 A rows, region max
  k_rnorm<<<8000, 256, 0, stream>>>(F, rinv);
  k_normmax<<<dim3(400, 4), 256, 0, stream>>>(F, rinv, A_kv, rmaxr, rmsum);
  k_normbf<<<400, 256, 0, stream>>>(rmaxr, rmsum, ubf);
  // temporal memory max-pool
  k_umax<<<dim3(TM_, 4), 256, 0, stream>>>(TMm, umax, msum);
  k_normbf<<<TM_, 256, 0, stream>>>(umax, msum, wnorm);
  // sim (bf16 prune) + fp32 rescore -> idx
  k_gemm<<<(MSIM/128) * (NSIM/128), 256, 0, stream>>>(ubf, wnorm, simc, NSIM/128, NSIM, 0, 60);
  k_cand<<<400, 256, 0, stream>>>(simc, cand, ccnt);
  k_rescore<<<400, 256, 0, stream>>>(rmaxr, rmsum, umax, msum, cand, ccnt, idxb);
  k_memfeat<<<400, 256, 0, stream>>>(umax, idxb, A_kv);
  // mega GEMM: [k|v|h1] for all kv rows   (overwrites overlay region)
  k_gemm<<<(MPAD/128) * (NW/128), 256, 0, stream>>>(A_kv, Wall, C2, NW/128, NW, 1, (MPAD/128)*(NW/128));
  // q, attention, QR selection, MLP head, gce, output
  k_q<<<B_*O_, 256, 0, stream>>>(labels, entW, entB, Wq, qbuf);
  k_attn<<<B_*H_, 256, 0, stream>>>(qbuf, C2, fpre);
  k_hilo<<<B_*O_*T_, 256, 0, stream>>>(qbuf, C2, hib, lob);
  k_z<<<MROWS/4, 256, 0, stream>>>(C2, b1, W2, b2, zbuf);
  k_gce<<<1, 256, 0, stream>>>(zbuf, hib, lob, labels, gbuf);
  k_out<<<B_*O_, 256, 0, stream>>>(fpre, Wo, gbuf, out);
}

// Round 2
// 576.967 us; speedup vs baseline: 1.2047x; 1.2047x over previous
//
#include <hip/hip_runtime.h>

#define B_   20
#define T_   20
#define RN   20
#define D_   4096
#define O_   16
#define E_   512
#define H_   8
#define DH   64
#define TM_  1900
#define NKV  420          // per-batch kv rows: 400 region + 20 mem
#define MROWS (B_*NKV)    // 8400
#define MPAD 8448         // 66 * 128
#define NW   1536         // Wk|Wv|W1 output channels
#define NSIM 1920         // 15 * 128 (TM padded)
#define MSIM 512          // 4 * 128 (B*T padded)
#define CAP  256
#define SIMK 4            // split-K factor for sim GEMM

using f32x4  = __attribute__((ext_vector_type(4))) float;
using bf16x8 = __attribute__((ext_vector_type(8))) __bf16;

__device__ __forceinline__ unsigned short f2bf(float f){
  unsigned u = __float_as_uint(f);
  u += 0x7fffu + ((u >> 16) & 1u);
  return (unsigned short)(u >> 16);
}

__device__ __forceinline__ void st_bf4(unsigned short* dst, float4 v){
  ushort4 o = make_ushort4(f2bf(v.x), f2bf(v.y), f2bf(v.z), f2bf(v.w));
  *(ushort4*)dst = o;
}

__device__ __forceinline__ float bsum256(float v, float* sh){
  int t = threadIdx.x;
  for (int o = 32; o; o >>= 1) v += __shfl_down(v, o, 64);
  __syncthreads();
  if ((t & 63) == 0) sh[t >> 6] = v;
  __syncthreads();
  return sh[0] + sh[1] + sh[2] + sh[3];
}

__device__ __forceinline__ float bmax256(float v, float* sh){
  int t = threadIdx.x;
  for (int o = 32; o; o >>= 1) v = fmaxf(v, __shfl_down(v, o, 64));
  __syncthreads();
  if ((t & 63) == 0) sh[t >> 6] = v;
  __syncthreads();
  return fmaxf(fmaxf(sh[0], sh[1]), fmaxf(sh[2], sh[3]));
}

__device__ __forceinline__ void gld16(const void* g, void* l){
  __builtin_amdgcn_global_load_lds(
      (const __attribute__((address_space(1))) unsigned int*)g,
      (__attribute__((address_space(3))) unsigned int*)l, 16, 0, 0);
}

// ---------- weight transpose+convert: W_all[n][k] = bf16(src[k][n]) ----------
__global__ __launch_bounds__(256) void k_wt(const float* __restrict__ Wk, const float* __restrict__ Wv,
                                            const float* __restrict__ W1, unsigned short* __restrict__ Wall){
  __shared__ float tile[32][33];
  int kb = blockIdx.x * 32, nb = blockIdx.y * 32;
  const float* src; int nc0;
  if (nb < 512)      { src = Wk; nc0 = nb; }
  else if (nb < 1024){ src = Wv; nc0 = nb - 512; }
  else               { src = W1; nc0 = nb - 1024; }
  int tx = threadIdx.x, ty = threadIdx.y;
  for (int j = 0; j < 4; ++j){
    int k = kb + ty + j*8;
    tile[ty + j*8][tx] = src[(size_t)k*E_ + nc0 + tx];
  }
  __syncthreads();
  for (int j = 0; j < 4; ++j){
    int n = nb + ty + j*8;
    int k = kb + tx;
    Wall[(size_t)n*D_ + k] = f2bf(tile[tx][ty + j*8]);
  }
}

// ---------- fused region pass: l2norm rows -> A_kv(bf16), region max -> rmaxr/rmsum/ubf ----------
__global__ __launch_bounds__(256) void k_region(const float* __restrict__ F, unsigned short* __restrict__ A,
                                                float* __restrict__ rmaxr, float* __restrict__ rmsum,
                                                unsigned short* __restrict__ ubf){
  int bt = blockIdx.x, t = threadIdx.x;
  if (bt >= 400){   // zero ubf pad rows (sim GEMM A pad)
    int4 z = make_int4(0,0,0,0);
    int4* row = (int4*)(ubf + (size_t)bt*D_);
    row[t] = z; row[t + 256] = z;
    return;
  }
  int b = bt / T_, tt = bt % T_;
  const float* fb = F + (size_t)bt*RN*D_;
  unsigned short* ab = A + ((size_t)b*NKV + (size_t)tt*RN)*D_;
  __shared__ float sh[4];
  float4 mx[4];
#pragma unroll
  for (int i = 0; i < 4; ++i) mx[i] = make_float4(-1e30f,-1e30f,-1e30f,-1e30f);
  for (int r = 0; r < RN; ++r){
    float4 v[4];
    float s = 0.f;
#pragma unroll
    for (int i = 0; i < 4; ++i){
      v[i] = *(const float4*)(fb + (size_t)r*D_ + i*1024 + t*4);
      s += v[i].x*v[i].x + v[i].y*v[i].y + v[i].z*v[i].z + v[i].w*v[i].w;
    }
    s = bsum256(s, sh);
    float ri = 1.f / fmaxf(sqrtf(s), 1e-12f);
#pragma unroll
    for (int i = 0; i < 4; ++i){
      v[i].x *= ri; v[i].y *= ri; v[i].z *= ri; v[i].w *= ri;
      st_bf4(ab + (size_t)r*D_ + i*1024 + t*4, v[i]);
      mx[i].x = fmaxf(mx[i].x, v[i].x); mx[i].y = fmaxf(mx[i].y, v[i].y);
      mx[i].z = fmaxf(mx[i].z, v[i].z); mx[i].w = fmaxf(mx[i].w, v[i].w);
    }
  }
  float s2 = 0.f;
#pragma unroll
  for (int i = 0; i < 4; ++i){
    *(float4*)(rmaxr + (size_t)bt*D_ + i*1024 + t*4) = mx[i];
    s2 += mx[i].x*mx[i].x + mx[i].y*mx[i].y + mx[i].z*mx[i].z + mx[i].w*mx[i].w;
  }
  s2 = bsum256(s2, sh);
  if (t == 0) rmsum[bt] = s2;
  float inv = 1.f / fmaxf(sqrtf(s2), 1e-12f);
#pragma unroll
  for (int i = 0; i < 4; ++i){
    float4 u = mx[i];
    u.x *= inv; u.y *= inv; u.z *= inv; u.w *= inv;
    st_bf4(ubf + (size_t)bt*D_ + i*1024 + t*4, u);
  }
}

// ---------- fused temporal-mem pass: frame max -> umax/msum, normalized -> wnorm ----------
__global__ __launch_bounds__(256) void k_mempool(const float* __restrict__ TMm, float* __restrict__ umax,
                                                 float* __restrict__ msum, unsigned short* __restrict__ wnorm){
  int m = blockIdx.x, t = threadIdx.x;
  if (m >= TM_){    // zero wnorm pad rows (sim GEMM B pad)
    int4 z = make_int4(0,0,0,0);
    int4* row = (int4*)(wnorm + (size_t)m*D_);
    row[t] = z; row[t + 256] = z;
    return;
  }
  const float* base = TMm + (size_t)m*T_*D_;
  float4 mx[4];
#pragma unroll
  for (int i = 0; i < 4; ++i) mx[i] = make_float4(-1e30f,-1e30f,-1e30f,-1e30f);
  for (int f = 0; f < T_; ++f){
#pragma unroll
    for (int i = 0; i < 4; ++i){
      float4 v = *(const float4*)(base + (size_t)f*D_ + i*1024 + t*4);
      mx[i].x = fmaxf(mx[i].x, v.x); mx[i].y = fmaxf(mx[i].y, v.y);
      mx[i].z = fmaxf(mx[i].z, v.z); mx[i].w = fmaxf(mx[i].w, v.w);
    }
  }
  float s = 0.f;
#pragma unroll
  for (int i = 0; i < 4; ++i){
    *(float4*)(umax + (size_t)m*D_ + i*1024 + t*4) = mx[i];
    s += mx[i].x*mx[i].x + mx[i].y*mx[i].y + mx[i].z*mx[i].z + mx[i].w*mx[i].w;
  }
  __shared__ float sh[4];
  s = bsum256(s, sh);
  if (t == 0) msum[m] = s;
  float inv = 1.f / fmaxf(sqrtf(s), 1e-12f);
#pragma unroll
  for (int i = 0; i < 4; ++i){
    float4 u = mx[i];
    u.x *= inv; u.y *= inv; u.z *= inv; u.w *= inv;
    st_bf4(wnorm + (size_t)m*D_ + i*1024 + t*4, u);
  }
}

// ---------- 128x128 bf16 MFMA GEMM with optional split-K ----------
// grid = nblk * nparts; part p handles K-tiles [p*nkt, (p+1)*nkt), writes C + p*cpart
__global__ __launch_bounds__(256, 2) void k_gemm(const unsigned short* __restrict__ A,
                                                 const unsigned short* __restrict__ Bw,
                                                 float* __restrict__ C,
                                                 int nNt, int ldc, int doswz, int nwg,
                                                 int nblk, int nkt, size_t cpart){
  __shared__ char lds[32768];
  int part = blockIdx.x / nblk;
  int bid  = blockIdx.x % nblk;
  if (doswz){ int q = nwg >> 3; bid = (bid & 7)*q + (bid >> 3); }
  int mt = bid / nNt, nt = bid % nNt;
  int tid = threadIdx.x, wv = tid >> 6, l = tid & 63;
  int wr = (wv >> 1) * 64, wc = (wv & 1) * 64;
  const char* Ab = (const char*)A + (size_t)mt*128*(size_t)(D_*2);
  const char* Bb = (const char*)Bw + (size_t)nt*128*(size_t)(D_*2);
  C += (size_t)part * cpart;
  f32x4 acc[4][4];
#pragma unroll
  for (int m = 0; m < 4; ++m)
#pragma unroll
    for (int n = 0; n < 4; ++n) acc[m][n] = (f32x4){0.f,0.f,0.f,0.f};
  int kt0 = part * nkt;
  for (int kt = kt0; kt < kt0 + nkt; ++kt){
    int ktoff = kt*128;
#pragma unroll
    for (int i = 0; i < 4; ++i){
      int idx = i*256 + tid;
      int row = idx >> 3, u = idx & 7;
      int ul = u ^ (row & 7);   // pre-swizzled global source (st-style XOR, G21)
      gld16(Ab + (size_t)row*(D_*2) + ktoff + ul*16, lds + i*4096 + wv*1024);
      gld16(Bb + (size_t)row*(D_*2) + ktoff + ul*16, lds + 16384 + i*4096 + wv*1024);
    }
    __syncthreads();
#pragma unroll
    for (int kk = 0; kk < 2; ++kk){
      bf16x8 av[4], bv[4];
#pragma unroll
      for (int m = 0; m < 4; ++m){
        int row = wr + m*16 + (l & 15);
        int u = (kk*4 + (l >> 4)) ^ (row & 7);
        av[m] = *(const bf16x8*)(lds + row*128 + u*16);
      }
#pragma unroll
      for (int n = 0; n < 4; ++n){
        int row = wc + n*16 + (l & 15);
        int u = (kk*4 + (l >> 4)) ^ (row & 7);
        bv[n] = *(const bf16x8*)(lds + 16384 + row*128 + u*16);
      }
#pragma unroll
      for (int m = 0; m < 4; ++m)
#pragma unroll
        for (int n = 0; n < 4; ++n)
          acc[m][n] = __builtin_amdgcn_mfma_f32_16x16x32_bf16(av[m], bv[n], acc[m][n], 0, 0, 0);
    }
    __syncthreads();
  }
  int rq = (l >> 4) * 4, cq = l & 15;
  size_t crow0 = (size_t)mt*128 + wr, ccol0 = (size_t)nt*128 + wc;
#pragma unroll
  for (int m = 0; m < 4; ++m)
#pragma unroll
    for (int n = 0; n < 4; ++n){
      size_t r0 = crow0 + m*16 + rq, c0 = ccol0 + n*16 + cq;
#pragma unroll
      for (int j = 0; j < 4; ++j)
        C[(r0 + j)*ldc + c0] = acc[m][n][j];
    }
}

// ---------- fused: sum split-K partials, margin-prune, fp32 rescore, gather mem row ----------
__global__ __launch_bounds__(256) void k_pick(const float* __restrict__ simp,
                                              const float* __restrict__ rmaxr, const float* __restrict__ rmsum,
                                              const float* __restrict__ umax, const float* __restrict__ msum,
                                              unsigned short* __restrict__ A){
  int bt = blockIdx.x, t = threadIdx.x;
  if (bt >= 400){   // zero A_kv pad rows 8400..8447
    int4 z = make_int4(0,0,0,0);
    int4* row = (int4*)(A + (size_t)(MROWS + bt - 400)*D_);
    row[t] = z; row[t + 256] = z;
    return;
  }
  __shared__ float srow[NSIM];
  __shared__ float sh[4];
  __shared__ int cnt;
  __shared__ int cl[CAP];
  for (int m = t; m < NSIM; m += 256){
    float s = 0.f;
#pragma unroll
    for (int p = 0; p < SIMK; ++p)
      s += simp[(size_t)p*MSIM*NSIM + (size_t)bt*NSIM + m];
    srow[m] = s;
  }
  if (t == 0) cnt = 0;
  __syncthreads();
  float mx = -1e30f;
  for (int m = t; m < TM_; m += 256) mx = fmaxf(mx, srow[m]);
  mx = bmax256(mx, sh);
  float thr = mx - 2.5e-4f;
  for (int m = t; m < TM_; m += 256){
    if (srow[m] >= thr){
      int p = atomicAdd(&cnt, 1);
      if (p < CAP) cl[p] = m;
    }
  }
  __syncthreads();
  int cn = cnt < CAP ? cnt : CAP;
  // fp32 rescore (same reduction order as round 1 — keep argmax bit-stable)
  float rinvv = 1.f / fmaxf(sqrtf(rmsum[bt]), 1e-12f);
  const float* a = rmaxr + (size_t)bt*D_;
  float best = -1e30f; int bestm = 0;
  for (int ci = 0; ci < cn; ++ci){
    int m = cl[ci];
    const float* wrow = umax + (size_t)m*D_;
    float p = 0.f;
    for (int i = t*4; i < D_; i += 1024){
      float4 av = *(const float4*)(a + i);
      float4 wv = *(const float4*)(wrow + i);
      p += av.x*wv.x + av.y*wv.y + av.z*wv.z + av.w*wv.w;
    }
    p = bsum256(p, sh);
    float sim = p * rinvv * (1.f / fmaxf(sqrtf(msum[m]), 1e-12f));
    if (sim > best || (sim == best && m < bestm) || ci == 0){ 
      if (sim > best || ci == 0 || (sim == best && m < bestm)){ best = sim; bestm = m; }
    }
  }
  // gather retrieved memory row -> A_kv (bf16, unnormalized max-pool)
  int b = bt / T_, tt = bt % T_;
  unsigned short* dst = A + ((size_t)b*NKV + 400 + tt)*D_;
  const float* src = umax + (size_t)bestm*D_;
#pragma unroll
  for (int i = 0; i < 4; ++i){
    size_t off = (size_t)i*1024 + t*4;
    float4 v = *(const float4*)(src + off);
    st_bf4(dst + off, v);
  }
}

// ---------- q = (onehot@entity_W + entity_b) @ Wq ----------
__global__ __launch_bounds__(256) void k_q(const int* __restrict__ labels, const float* __restrict__ entW,
                                           const float* __restrict__ entB, const float* __restrict__ Wq,
                                           float* __restrict__ q){
  int bo = blockIdx.x, t = threadIdx.x;
  __shared__ float qe[E_];
  int lab = labels[bo];
  float sel = (lab != 0) ? 1.f : 0.f;
  qe[t]       = sel * entW[(size_t)lab*E_ + t]       + entB[t];
  qe[t + 256] = sel * entW[(size_t)lab*E_ + t + 256] + entB[t + 256];
  __syncthreads();
  float a0 = 0.f, a1 = 0.f;
  for (int ep = 0; ep < E_; ++ep){
    float r = qe[ep];
    a0 += r * Wq[(size_t)ep*E_ + t];
    a1 += r * Wq[(size_t)ep*E_ + t + 256];
  }
  q[(size_t)bo*E_ + t] = a0;
  q[(size_t)bo*E_ + t + 256] = a1;
}

// ---------- attention per (b,h): scores -> softmax -> attn@v (v staged via LDS) ----------
__global__ __launch_bounds__(256) void k_attn(const float* __restrict__ q, const float* __restrict__ c2,
                                              float* __restrict__ fpre){
  int bh = blockIdx.x; int b = bh >> 3, h = bh & 7;
  int t = threadIdx.x, w = t >> 6, l = t & 63;
  __shared__ float qhp[O_][DH + 1];
  __shared__ float kb[105][DH + 1];
  __shared__ float sc[O_][NKV];
  for (int i = t; i < O_*DH; i += 256){
    int o = i >> 6, d = i & 63;
    qhp[o][d] = q[((size_t)(b*O_ + o))*E_ + h*DH + d] * 0.125f;
  }
  __syncthreads();
  for (int c = 0; c < 4; ++c){
    for (int i = t; i < 105*DH; i += 256){
      int j = i >> 6, d = i & 63;
      kb[j][d] = c2[((size_t)(b*NKV + c*105 + j))*NW + h*DH + d];
    }
    __syncthreads();
    for (int i = t; i < O_*105; i += 256){
      int o = i / 105, j = i % 105;
      float acc = 0.f;
      for (int d = 0; d < DH; ++d) acc += qhp[o][d] * kb[j][d];
      sc[o][c*105 + j] = acc;
    }
    __syncthreads();
  }
  for (int oi = 0; oi < 4; ++oi){
    int o = w + oi*4;
    float mx = -1e30f;
    for (int n = l; n < NKV; n += 64) mx = fmaxf(mx, sc[o][n]);
    for (int off = 32; off; off >>= 1) mx = fmaxf(mx, __shfl_xor(mx, off, 64));
    float sum = 0.f;
    for (int n = l; n < NKV; n += 64){ float e = expf(sc[o][n] - mx); sc[o][n] = e; sum += e; }
    for (int off = 32; off; off >>= 1) sum += __shfl_xor(sum, off, 64);
    float inv = 1.f / sum;
    for (int n = l; n < NKV; n += 64) sc[o][n] *= inv;
  }
  __syncthreads();
  float acc[4] = {0.f, 0.f, 0.f, 0.f};
  for (int c = 0; c < 4; ++c){
    for (int i = t; i < 105*DH; i += 256){
      int j = i >> 6, d = i & 63;
      kb[j][d] = c2[((size_t)(b*NKV + c*105 + j))*NW + E_ + h*DH + d];
    }
    __syncthreads();
#pragma unroll
    for (int og = 0; og < 4; ++og){
      int o = og*4 + w;
      float a = 0.f;
      for (int j = 0; j < 105; ++j) a += sc[o][c*105 + j] * kb[j][l];
      acc[og] += a;
    }
    __syncthreads();
  }
#pragma unroll
  for (int og = 0; og < 4; ++og){
    int o = og*4 + w;
    fpre[((size_t)(b*O_ + o))*E_ + h*DH + l] = acc[og];
  }
}

// ---------- QR argmax/argmin per (b,t): k rows staged in LDS, reused by all 16 o ----------
__global__ __launch_bounds__(256) void k_hilo(const float* __restrict__ q, const float* __restrict__ c2,
                                              int* __restrict__ hi, int* __restrict__ lo){
  int bid = blockIdx.x;             // b*T + tt
  int b = bid / T_, tt = bid % T_;
  int t = threadIdx.x;
  __shared__ float kl[RN][E_ + 1];
  __shared__ float qr[O_][RN];
  for (int i = t; i < RN*E_; i += 256){
    int r = i >> 9, e = i & 511;
    kl[r][e] = c2[((size_t)(b*NKV + tt*RN + r))*NW + e];
  }
  __syncthreads();
  // 320 (o,r) pairs; thread t does pair t, threads t<64 also pair 256+t
#pragma unroll
  for (int pp = 0; pp < 2; ++pp){
    int p = t + pp*256;
    if (p < O_*RN){
      int o = p / RN, r = p % RN;
      const float* qrow = q + ((size_t)(b*O_ + o))*E_;
      float acc = 0.f;
      for (int e = 0; e < E_; ++e) acc += qrow[e] * kl[r][e];
      qr[o][r] = acc;
    }
  }
  __syncthreads();
  if (t < O_){
    int o = t;
    float bh = qr[o][0], bl = qr[o][0]; int ih = 0, il = 0;
#pragma unroll
    for (int r = 1; r < RN; ++r){
      float v = qr[o][r];
      if (v > bh){ bh = v; ih = r; }
      if (v < bl){ bl = v; il = r; }
    }
    int rowbase = b*NKV + tt*RN;
    int outi = (b*O_ + o)*T_ + tt;
    hi[outi] = rowbase + ih;
    lo[outi] = rowbase + il;
  }
}

// ---------- z = sigmoid(tanh(h1+b1)@W2 + b2) — region rows only ----------
__global__ __launch_bounds__(256) void k_z(const float* __restrict__ c2, const float* __restrict__ b1,
                                           const float* __restrict__ W2, const float* __restrict__ b2,
                                           float* __restrict__ z){
  int g = blockIdx.x*4 + (threadIdx.x >> 6);   // region row id 0..7999
  int l = threadIdx.x & 63;
  int b = g / 400, j = g % 400;
  int row = b*NKV + j;
  const float* hrow = c2 + (size_t)row*NW + 1024;
  float acc = 0.f;
  for (int e = l; e < E_; e += 64) acc += tanhf(hrow[e] + b1[e]) * W2[e];
  for (int off = 32; off; off >>= 1) acc += __shfl_down(acc, off, 64);
  if (l == 0) z[row] = 1.f / (1.f + expf(-(acc + b2[0])));
}

// ---------- gce scalar (pre-scaled by beta) ----------
__global__ __launch_bounds__(256) void k_gce(const float* __restrict__ z, const int* __restrict__ hi,
                                             const int* __restrict__ lo, const int* __restrict__ labels,
                                             float* __restrict__ gout){
  __shared__ float vb[B_];
  __shared__ int cb[B_];
  int t = threadIdx.x;
  if (t < B_){ vb[t] = 0.f; cb[t] = 0; }
  __syncthreads();
  for (int p = t; p < B_*O_; p += 256){
    int b = p / O_;
    if (labels[p] != 0){
      float acc = 0.f;
      for (int tt = 0; tt < T_; ++tt){
        float shi = z[hi[p*T_ + tt]];
        float slo = z[lo[p*T_ + tt]];
        acc += (1.f - __powf(shi + 1e-7f, 0.7f)) / 0.7f;
        acc += (1.f - __powf(1.f - slo + 1e-7f, 0.7f)) / 0.7f;
      }
      atomicAdd(&vb[b], acc / (float)T_);
      atomicAdd(&cb[b], 1);
    }
  }
  __syncthreads();
  if (t == 0){
    float g = 0.f;
    for (int b = 0; b < B_; ++b) g += vb[b] / fmaxf((float)cb[b], 1.f);
    gout[0] = 0.5f * (g / (float)B_);
  }
}

// ---------- out = fpre @ Wo + beta*gce ----------
__global__ __launch_bounds__(256) void k_out(const float* __restrict__ fpre, const float* __restrict__ Wo,
                                             const float* __restrict__ gce, float* __restrict__ out){
  int bo = blockIdx.x, t = threadIdx.x;
  __shared__ float row[E_];
  row[t] = fpre[(size_t)bo*E_ + t];
  row[t + 256] = fpre[(size_t)bo*E_ + t + 256];
  __syncthreads();
  float g = gce[0];
  float a0 = 0.f, a1 = 0.f;
  for (int ep = 0; ep < E_; ++ep){
    float r = row[ep];
    a0 += r * Wo[(size_t)ep*E_ + t];
    a1 += r * Wo[(size_t)ep*E_ + t + 256];
  }
  out[(size_t)bo*E_ + t] = a0 + g;
  out[(size_t)bo*E_ + t + 256] = a1 + g;
}

extern "C" void kernel_launch(void* const* d_in, const int* in_sizes, int n_in,
                              void* d_out, int out_size, void* d_ws, size_t ws_size,
                              hipStream_t stream) {
  (void)in_sizes; (void)n_in; (void)out_size; (void)ws_size;
  const float* F    = (const float*)d_in[0];
  const int*   labels = (const int*)d_in[1];
  const float* TMm  = (const float*)d_in[2];
  const float* entW = (const float*)d_in[3];
  const float* entB = (const float*)d_in[4];
  const float* Wq   = (const float*)d_in[5];
  const float* Wk   = (const float*)d_in[6];
  const float* Wv   = (const float*)d_in[7];
  const float* Wo   = (const float*)d_in[8];
  const float* W1   = (const float*)d_in[9];
  const float* b1   = (const float*)d_in[10];
  const float* W2   = (const float*)d_in[11];
  const float* b2   = (const float*)d_in[12];
  float* out = (float*)d_out;

  size_t off = 0;
  char* wsb = (char*)d_ws;
  auto alloc = [&](size_t bytes) -> char* {
    char* p = wsb + off; off += (bytes + 255) & ~(size_t)255; return p;
  };
  unsigned short* A_kv = (unsigned short*)alloc((size_t)MPAD * D_ * 2);
  unsigned short* Wall = (unsigned short*)alloc((size_t)NW * D_ * 2);
  float* umax          = (float*)alloc((size_t)TM_ * D_ * 4);
  char*  c2reg         = alloc((size_t)MPAD * NW * 4);      // overlay region (51.9 MB)
  float* C2    = (float*)c2reg;
  unsigned short* wnorm = (unsigned short*)c2reg;                       // 15,728,640 B
  float* simp  = (float*)(c2reg + 15728640);                            // 15,728,640 B (4 partials)
  unsigned short* ubf = (unsigned short*)(c2reg + 31457280);            //  4,194,304 B
  float* rmaxr = (float*)(c2reg + 35651584);                            //  6,553,600 B (ends 42.2 MB)
  float* qbuf  = (float*)alloc((size_t)B_ * O_ * E_ * 4);
  float* fpre  = (float*)alloc((size_t)B_ * O_ * E_ * 4);
  float* rmsum = (float*)alloc(400 * 4);
  float* msum  = (float*)alloc(TM_ * 4);
  int*   hib   = (int*)alloc(6400 * 4);
  int*   lob   = (int*)alloc(6400 * 4);
  float* zbuf  = (float*)alloc((size_t)MROWS * 4);
  float* gbuf  = (float*)alloc(256);

  // weights -> bf16 [N][K]
  k_wt<<<dim3(D_/32, NW/32), dim3(32, 8), 0, stream>>>(Wk, Wv, W1, Wall);
  // region features: single pass (norm + A_kv + region max + ubf + rmsum); grid pads ubf
  k_region<<<MSIM, 256, 0, stream>>>(F, A_kv, rmaxr, rmsum, ubf);
  // temporal memory: single pass (max-pool + msum + wnorm); grid pads wnorm
  k_mempool<<<NSIM/128*128 == NSIM ? NSIM : NSIM, 256, 0, stream>>>(TMm, umax, msum, wnorm);
  // sim GEMM, split-K=4 -> partials
  k_gemm<<<(MSIM/128)*(NSIM/128)*SIMK, 256, 0, stream>>>(ubf, wnorm, simp, NSIM/128, NSIM, 0, 60,
                                                         (MSIM/128)*(NSIM/128), (D_/64)/SIMK,
                                                         (size_t)MSIM*NSIM);
  // fused reduce+prune+rescore+gather (grid pads A_kv)
  k_pick<<<448, 256, 0, stream>>>(simp, rmaxr, rmsum, umax, msum, A_kv);
  // mega GEMM: [k|v|h1] for all kv rows (overwrites overlay region)
  k_gemm<<<(MPAD/128)*(NW/128), 256, 0, stream>>>(A_kv, Wall, C2, NW/128, NW, 1,
                                                  (MPAD/128)*(NW/128),
                                                  (MPAD/128)*(NW/128), D_/64, 0);
  // q, attention, QR selection, MLP head, gce, output
  k_q<<<B_*O_, 256, 0, stream>>>(labels, entW, entB, Wq, qbuf);
  k_attn<<<B_*H_, 256, 0, stream>>>(qbuf, C2, fpre);
  k_hilo<<<B_*T_, 256, 0, stream>>>(qbuf, C2, hib, lob);
  k_z<<<2000, 256, 0, stream>>>(C2, b1, W2, b2, zbuf);
  k_gce<<<1, 256, 0, stream>>>(zbuf, hib, lob, labels, gbuf);
  k_out<<<B_*O_, 256, 0, stream>>>(fpre, Wo, gbuf, out);
}

// Round 3
// 510.725 us; speedup vs baseline: 1.3609x; 1.1297x over previous
//
#include <hip/hip_runtime.h>

#define B_   20
#define T_   20
#define RN   20
#define D_   4096
#define O_   16
#define E_   512
#define H_   8
#define DH   64
#define TM_  1900
#define NKV  420          // per-batch kv rows: 400 region + 20 mem
#define MROWS (B_*NKV)    // 8400
#define MPAD 8448         // 66 * 128
#define NW   1536         // Wk|Wv|W1 output channels
#define NSIM 1920         // 15 * 128 (TM padded)
#define MSIM 512          // 4 * 128 (B*T padded)
#define CAP  256
#define SIMK 8            // split-K factor for sim GEMM

using f32x4  = __attribute__((ext_vector_type(4))) float;
using bf16x8 = __attribute__((ext_vector_type(8))) __bf16;

__device__ __forceinline__ unsigned short f2bf(float f){
  unsigned u = __float_as_uint(f);
  u += 0x7fffu + ((u >> 16) & 1u);
  return (unsigned short)(u >> 16);
}

__device__ __forceinline__ void st_bf4(unsigned short* dst, float4 v){
  ushort4 o = make_ushort4(f2bf(v.x), f2bf(v.y), f2bf(v.z), f2bf(v.w));
  *(ushort4*)dst = o;
}

__device__ __forceinline__ float bsum256(float v, float* sh){
  int t = threadIdx.x;
  for (int o = 32; o; o >>= 1) v += __shfl_down(v, o, 64);
  __syncthreads();
  if ((t & 63) == 0) sh[t >> 6] = v;
  __syncthreads();
  return sh[0] + sh[1] + sh[2] + sh[3];
}

__device__ __forceinline__ float bmax256(float v, float* sh){
  int t = threadIdx.x;
  for (int o = 32; o; o >>= 1) v = fmaxf(v, __shfl_down(v, o, 64));
  __syncthreads();
  if ((t & 63) == 0) sh[t >> 6] = v;
  __syncthreads();
  return fmaxf(fmaxf(sh[0], sh[1]), fmaxf(sh[2], sh[3]));
}

__device__ __forceinline__ void gld16(const void* g, void* l){
  __builtin_amdgcn_global_load_lds(
      (const __attribute__((address_space(1))) unsigned int*)g,
      (__attribute__((address_space(3))) unsigned int*)l, 16, 0, 0);
}

// ================= fused preprocessing (horizontal fusion) =================
// blocks [0,1920): temporal-mem max-pool -> umax/msum/wnorm (+pad)
// blocks [1920,2432): region pass -> A_kv, rmaxr, rmsum, ubf (+pad)
// blocks [2432,8576): weight transpose+convert -> Wall
// blocks [8576,8896): q = (onehot@entity_W + b) @ Wq
__global__ __launch_bounds__(256) void k_pre(
    const float* __restrict__ F, const float* __restrict__ TMm,
    const float* __restrict__ Wk, const float* __restrict__ Wv, const float* __restrict__ W1,
    unsigned short* __restrict__ Wall,
    unsigned short* __restrict__ A, float* __restrict__ rmaxr, float* __restrict__ rmsum,
    unsigned short* __restrict__ ubf,
    float* __restrict__ umax, float* __restrict__ msum, unsigned short* __restrict__ wnorm,
    const int* __restrict__ labels, const float* __restrict__ entW, const float* __restrict__ entB,
    const float* __restrict__ Wq, float* __restrict__ q){
  __shared__ char smem[4352];
  int bid = blockIdx.x, t = threadIdx.x;
  if (bid < 1920){
    // ---- temporal-mem frame max-pool ----
    int m = bid;
    if (m >= TM_){
      int4 zz = make_int4(0,0,0,0);
      int4* row = (int4*)(wnorm + (size_t)m*D_);
      row[t] = zz; row[t + 256] = zz;
      return;
    }
    float* sh = (float*)smem;
    const float* base = TMm + (size_t)m*T_*D_;
    float4 mx[4];
#pragma unroll
    for (int i = 0; i < 4; ++i) mx[i] = make_float4(-1e30f,-1e30f,-1e30f,-1e30f);
    for (int f = 0; f < T_; ++f){
#pragma unroll
      for (int i = 0; i < 4; ++i){
        float4 v = *(const float4*)(base + (size_t)f*D_ + i*1024 + t*4);
        mx[i].x = fmaxf(mx[i].x, v.x); mx[i].y = fmaxf(mx[i].y, v.y);
        mx[i].z = fmaxf(mx[i].z, v.z); mx[i].w = fmaxf(mx[i].w, v.w);
      }
    }
    float s = 0.f;
#pragma unroll
    for (int i = 0; i < 4; ++i){
      *(float4*)(umax + (size_t)m*D_ + i*1024 + t*4) = mx[i];
      s += mx[i].x*mx[i].x + mx[i].y*mx[i].y + mx[i].z*mx[i].z + mx[i].w*mx[i].w;
    }
    s = bsum256(s, sh);
    if (t == 0) msum[m] = s;
    float inv = 1.f / fmaxf(sqrtf(s), 1e-12f);
#pragma unroll
    for (int i = 0; i < 4; ++i){
      float4 u = mx[i];
      u.x *= inv; u.y *= inv; u.z *= inv; u.w *= inv;
      st_bf4(wnorm + (size_t)m*D_ + i*1024 + t*4, u);
    }
  } else if (bid < 2432){
    // ---- region pass: l2norm rows -> A_kv(bf16), region max -> rmaxr/rmsum/ubf ----
    int bt = bid - 1920;
    if (bt >= 400){
      int4 zz = make_int4(0,0,0,0);
      int4* row = (int4*)(ubf + (size_t)bt*D_);
      row[t] = zz; row[t + 256] = zz;
      return;
    }
    float* sh = (float*)smem;
    int b = bt / T_, tt = bt % T_;
    const float* fb = F + (size_t)bt*RN*D_;
    unsigned short* ab = A + ((size_t)b*NKV + (size_t)tt*RN)*D_;
    float4 mx[4];
#pragma unroll
    for (int i = 0; i < 4; ++i) mx[i] = make_float4(-1e30f,-1e30f,-1e30f,-1e30f);
    for (int r = 0; r < RN; ++r){
      float4 v[4];
      float s = 0.f;
#pragma unroll
      for (int i = 0; i < 4; ++i){
        v[i] = *(const float4*)(fb + (size_t)r*D_ + i*1024 + t*4);
        s += v[i].x*v[i].x + v[i].y*v[i].y + v[i].z*v[i].z + v[i].w*v[i].w;
      }
      s = bsum256(s, sh);
      float ri = 1.f / fmaxf(sqrtf(s), 1e-12f);
#pragma unroll
      for (int i = 0; i < 4; ++i){
        v[i].x *= ri; v[i].y *= ri; v[i].z *= ri; v[i].w *= ri;
        st_bf4(ab + (size_t)r*D_ + i*1024 + t*4, v[i]);
        mx[i].x = fmaxf(mx[i].x, v[i].x); mx[i].y = fmaxf(mx[i].y, v[i].y);
        mx[i].z = fmaxf(mx[i].z, v[i].z); mx[i].w = fmaxf(mx[i].w, v[i].w);
      }
    }
    float s2 = 0.f;
#pragma unroll
    for (int i = 0; i < 4; ++i){
      *(float4*)(rmaxr + (size_t)bt*D_ + i*1024 + t*4) = mx[i];
      s2 += mx[i].x*mx[i].x + mx[i].y*mx[i].y + mx[i].z*mx[i].z + mx[i].w*mx[i].w;
    }
    s2 = bsum256(s2, sh);
    if (t == 0) rmsum[bt] = s2;
    float inv = 1.f / fmaxf(sqrtf(s2), 1e-12f);
#pragma unroll
    for (int i = 0; i < 4; ++i){
      float4 u = mx[i];
      u.x *= inv; u.y *= inv; u.z *= inv; u.w *= inv;
      st_bf4(ubf + (size_t)bt*D_ + i*1024 + t*4, u);
    }
  } else if (bid < 8576){
    // ---- weight transpose+convert: Wall[n][k] = bf16(src[k][n]) ----
    int wti = bid - 2432;
    float* tile = (float*)smem;          // [32][33]
    int kb = (wti & 127) * 32, nb = (wti >> 7) * 32;
    const float* src; int nc0;
    if (nb < 512)      { src = Wk; nc0 = nb; }
    else if (nb < 1024){ src = Wv; nc0 = nb - 512; }
    else               { src = W1; nc0 = nb - 1024; }
    int tx = t & 31, ty = t >> 5;
#pragma unroll
    for (int j = 0; j < 4; ++j){
      int k = kb + ty + j*8;
      tile[(ty + j*8)*33 + tx] = src[(size_t)k*E_ + nc0 + tx];
    }
    __syncthreads();
#pragma unroll
    for (int j = 0; j < 4; ++j){
      int n = nb + ty + j*8;
      int k = kb + tx;
      Wall[(size_t)n*D_ + k] = f2bf(tile[tx*33 + ty + j*8]);
    }
  } else {
    // ---- q = (onehot@entity_W + entity_b) @ Wq ----
    int bo = bid - 8576;
    float* qe = (float*)smem;
    int lab = labels[bo];
    float sel = (lab != 0) ? 1.f : 0.f;
    qe[t]       = sel * entW[(size_t)lab*E_ + t]       + entB[t];
    qe[t + 256] = sel * entW[(size_t)lab*E_ + t + 256] + entB[t + 256];
    __syncthreads();
    float a0 = 0.f, a1 = 0.f;
    for (int ep = 0; ep < E_; ++ep){
      float r = qe[ep];
      a0 += r * Wq[(size_t)ep*E_ + t];
      a1 += r * Wq[(size_t)ep*E_ + t + 256];
    }
    q[(size_t)bo*E_ + t] = a0;
    q[(size_t)bo*E_ + t + 256] = a1;
  }
}

// ---------- 128x128 bf16 MFMA GEMM with optional split-K ----------
// grid = nblk * nparts; part p handles K-tiles [p*nkt, (p+1)*nkt), writes C + p*cpart
__global__ __launch_bounds__(256, 2) void k_gemm(const unsigned short* __restrict__ A,
                                                 const unsigned short* __restrict__ Bw,
                                                 float* __restrict__ C,
                                                 int nNt, int ldc, int doswz, int nwg,
                                                 int nblk, int nkt, size_t cpart){
  __shared__ char lds[32768];
  int part = blockIdx.x / nblk;
  int bid  = blockIdx.x % nblk;
  if (doswz){ int q = nwg >> 3; bid = (bid & 7)*q + (bid >> 3); }
  int mt = bid / nNt, nt = bid % nNt;
  int tid = threadIdx.x, wv = tid >> 6, l = tid & 63;
  int wr = (wv >> 1) * 64, wc = (wv & 1) * 64;
  const char* Ab = (const char*)A + (size_t)mt*128*(size_t)(D_*2);
  const char* Bb = (const char*)Bw + (size_t)nt*128*(size_t)(D_*2);
  C += (size_t)part * cpart;
  f32x4 acc[4][4];
#pragma unroll
  for (int m = 0; m < 4; ++m)
#pragma unroll
    for (int n = 0; n < 4; ++n) acc[m][n] = (f32x4){0.f,0.f,0.f,0.f};
  int kt0 = part * nkt;
  for (int kt = kt0; kt < kt0 + nkt; ++kt){
    int ktoff = kt*128;
#pragma unroll
    for (int i = 0; i < 4; ++i){
      int idx = i*256 + tid;
      int row = idx >> 3, u = idx & 7;
      int ul = u ^ (row & 7);   // pre-swizzled global source (st-style XOR, G21)
      gld16(Ab + (size_t)row*(D_*2) + ktoff + ul*16, lds + i*4096 + wv*1024);
      gld16(Bb + (size_t)row*(D_*2) + ktoff + ul*16, lds + 16384 + i*4096 + wv*1024);
    }
    __syncthreads();
#pragma unroll
    for (int kk = 0; kk < 2; ++kk){
      bf16x8 av[4], bv[4];
#pragma unroll
      for (int m = 0; m < 4; ++m){
        int row = wr + m*16 + (l & 15);
        int u = (kk*4 + (l >> 4)) ^ (row & 7);
        av[m] = *(const bf16x8*)(lds + row*128 + u*16);
      }
#pragma unroll
      for (int n = 0; n < 4; ++n){
        int row = wc + n*16 + (l & 15);
        int u = (kk*4 + (l >> 4)) ^ (row & 7);
        bv[n] = *(const bf16x8*)(lds + 16384 + row*128 + u*16);
      }
#pragma unroll
      for (int m = 0; m < 4; ++m)
#pragma unroll
        for (int n = 0; n < 4; ++n)
          acc[m][n] = __builtin_amdgcn_mfma_f32_16x16x32_bf16(av[m], bv[n], acc[m][n], 0, 0, 0);
    }
    __syncthreads();
  }
  int rq = (l >> 4) * 4, cq = l & 15;
  size_t crow0 = (size_t)mt*128 + wr, ccol0 = (size_t)nt*128 + wc;
#pragma unroll
  for (int m = 0; m < 4; ++m)
#pragma unroll
    for (int n = 0; n < 4; ++n){
      size_t r0 = crow0 + m*16 + rq, c0 = ccol0 + n*16 + cq;
#pragma unroll
      for (int j = 0; j < 4; ++j)
        C[(r0 + j)*ldc + c0] = acc[m][n][j];
    }
}

// ---------- fused: sum split-K partials, margin-prune, fp32 rescore, gather mem row ----------
__global__ __launch_bounds__(256) void k_pick(const float* __restrict__ simp,
                                              const float* __restrict__ rmaxr, const float* __restrict__ rmsum,
                                              const float* __restrict__ umax, const float* __restrict__ msum,
                                              unsigned short* __restrict__ A){
  int bt = blockIdx.x, t = threadIdx.x;
  if (bt >= 400){   // zero A_kv pad rows 8400..8447
    int4 z = make_int4(0,0,0,0);
    int4* row = (int4*)(A + (size_t)(MROWS + bt - 400)*D_);
    row[t] = z; row[t + 256] = z;
    return;
  }
  __shared__ float srow[NSIM];
  __shared__ float sh[4];
  __shared__ int cnt;
  __shared__ int cl[CAP];
  for (int m = t; m < NSIM; m += 256){
    float s = 0.f;
#pragma unroll
    for (int p = 0; p < SIMK; ++p)
      s += simp[(size_t)p*MSIM*NSIM + (size_t)bt*NSIM + m];
    srow[m] = s;
  }
  if (t == 0) cnt = 0;
  __syncthreads();
  float mx = -1e30f;
  for (int m = t; m < TM_; m += 256) mx = fmaxf(mx, srow[m]);
  mx = bmax256(mx, sh);
  float thr = mx - 2.5e-4f;
  for (int m = t; m < TM_; m += 256){
    if (srow[m] >= thr){
      int p = atomicAdd(&cnt, 1);
      if (p < CAP) cl[p] = m;
    }
  }
  __syncthreads();
  int cn = cnt < CAP ? cnt : CAP;
  // fp32 rescore, total-order tie-break -> deterministic exact argmax
  float rinvv = 1.f / fmaxf(sqrtf(rmsum[bt]), 1e-12f);
  const float* a = rmaxr + (size_t)bt*D_;
  float best = -1e30f; int bestm = 0x7fffffff;
  for (int ci = 0; ci < cn; ++ci){
    int m = cl[ci];
    const float* wrow = umax + (size_t)m*D_;
    float p = 0.f;
    for (int i = t*4; i < D_; i += 1024){
      float4 av = *(const float4*)(a + i);
      float4 wv = *(const float4*)(wrow + i);
      p += av.x*wv.x + av.y*wv.y + av.z*wv.z + av.w*wv.w;
    }
    p = bsum256(p, sh);
    float sim = p * rinvv * (1.f / fmaxf(sqrtf(msum[m]), 1e-12f));
    if (sim > best || (sim == best && m < bestm)){ best = sim; bestm = m; }
  }
  // gather retrieved memory row -> A_kv (bf16, unnormalized max-pool)
  int b = bt / T_, tt = bt % T_;
  unsigned short* dst = A + ((size_t)b*NKV + 400 + tt)*D_;
  const float* src = umax + (size_t)bestm*D_;
#pragma unroll
  for (int i = 0; i < 4; ++i){
    size_t off = (size_t)i*1024 + t*4;
    float4 v = *(const float4*)(src + off);
    st_bf4(dst + off, v);
  }
}

// ================= fused post-GEMM (horizontal fusion) =================
// blocks [0,160): attention per (b,h)
// blocks [160,560): QR argmax/argmin per (b,t)
// blocks [560,2560): z-MLP over region rows (4/block)
__global__ __launch_bounds__(256) void k_post(const float* __restrict__ q, const float* __restrict__ c2,
                                              float* __restrict__ fpre, int* __restrict__ hi,
                                              int* __restrict__ lo, const float* __restrict__ b1,
                                              const float* __restrict__ W2, const float* __restrict__ b2,
                                              float* __restrict__ z){
  __shared__ char smem[58368];
  int bid = blockIdx.x, t = threadIdx.x;
  if (bid < 160){
    // ---- attention ----
    int b = bid >> 3, h = bid & 7;
    int w = t >> 6, l = t & 63;
    float* qhp = (float*)smem;               // [16][65]
    float* kb  = (float*)(smem + 4160);      // [105][65]
    float* sc  = (float*)(smem + 31460);     // [16][420]
    for (int i = t; i < O_*DH; i += 256){
      int o = i >> 6, d = i & 63;
      qhp[o*65 + d] = q[((size_t)(b*O_ + o))*E_ + h*DH + d] * 0.125f;
    }
    __syncthreads();
    for (int c = 0; c < 4; ++c){
      for (int i = t; i < 105*DH; i += 256){
        int j = i >> 6, d = i & 63;
        kb[j*65 + d] = c2[((size_t)(b*NKV + c*105 + j))*NW + h*DH + d];
      }
      __syncthreads();
      for (int i = t; i < O_*105; i += 256){
        int o = i / 105, j = i % 105;
        float acc = 0.f;
        for (int d = 0; d < DH; ++d) acc += qhp[o*65 + d] * kb[j*65 + d];
        sc[o*420 + c*105 + j] = acc;
      }
      __syncthreads();
    }
    for (int oi = 0; oi < 4; ++oi){
      int o = w + oi*4;
      float mx = -1e30f;
      for (int n = l; n < NKV; n += 64) mx = fmaxf(mx, sc[o*420 + n]);
      for (int of = 32; of; of >>= 1) mx = fmaxf(mx, __shfl_xor(mx, of, 64));
      float sum = 0.f;
      for (int n = l; n < NKV; n += 64){ float e = expf(sc[o*420 + n] - mx); sc[o*420 + n] = e; sum += e; }
      for (int of = 32; of; of >>= 1) sum += __shfl_xor(sum, of, 64);
      float inv = 1.f / sum;
      for (int n = l; n < NKV; n += 64) sc[o*420 + n] *= inv;
    }
    __syncthreads();
    float acc[4] = {0.f, 0.f, 0.f, 0.f};
    for (int c = 0; c < 4; ++c){
      for (int i = t; i < 105*DH; i += 256){
        int j = i >> 6, d = i & 63;
        kb[j*65 + d] = c2[((size_t)(b*NKV + c*105 + j))*NW + E_ + h*DH + d];
      }
      __syncthreads();
#pragma unroll
      for (int og = 0; og < 4; ++og){
        int o = og*4 + w;
        float a = 0.f;
        for (int j = 0; j < 105; ++j) a += sc[o*420 + c*105 + j] * kb[j*65 + l];
        acc[og] += a;
      }
      __syncthreads();
    }
#pragma unroll
    for (int og = 0; og < 4; ++og){
      int o = og*4 + w;
      fpre[((size_t)(b*O_ + o))*E_ + h*DH + l] = acc[og];
    }
  } else if (bid < 560){
    // ---- hi/lo region selection ----
    int bt = bid - 160;
    int b = bt / T_, tt = bt % T_;
    float* kl = (float*)smem;                // [20][513]
    float* qr = (float*)(smem + 41040);      // [16][20]
    for (int i = t; i < RN*E_; i += 256){
      int r = i >> 9, e = i & 511;
      kl[r*513 + e] = c2[((size_t)(b*NKV + tt*RN + r))*NW + e];
    }
    __syncthreads();
#pragma unroll
    for (int pp = 0; pp < 2; ++pp){
      int p = t + pp*256;
      if (p < O_*RN){
        int o = p / RN, r = p % RN;
        const float* qrow = q + ((size_t)(b*O_ + o))*E_;
        float acc = 0.f;
        for (int e = 0; e < E_; ++e) acc += qrow[e] * kl[r*513 + e];
        qr[o*20 + r] = acc;
      }
    }
    __syncthreads();
    if (t < O_){
      int o = t;
      float bh = qr[o*20], bl = qr[o*20]; int ih = 0, il = 0;
#pragma unroll
      for (int r = 1; r < RN; ++r){
        float v = qr[o*20 + r];
        if (v > bh){ bh = v; ih = r; }
        if (v < bl){ bl = v; il = r; }
      }
      int rowbase = b*NKV + tt*RN;
      int outi = (b*O_ + o)*T_ + tt;
      hi[outi] = rowbase + ih;
      lo[outi] = rowbase + il;
    }
  } else {
    // ---- z = sigmoid(tanh(h1+b1)@W2 + b2), region rows only ----
    int g = (bid - 560)*4 + (t >> 6);
    int l = t & 63;
    int b = g / 400, j = g % 400;
    int row = b*NKV + j;
    const float* hrow = c2 + (size_t)row*NW + 1024;
    float acc = 0.f;
    for (int e = l; e < E_; e += 64) acc += tanhf(hrow[e] + b1[e]) * W2[e];
    for (int of = 32; of; of >>= 1) acc += __shfl_down(acc, of, 64);
    if (l == 0) z[row] = 1.f / (1.f + expf(-(acc + b2[0])));
  }
}

// ---------- out = fpre @ Wo + beta*gce (gce recomputed per block) ----------
__global__ __launch_bounds__(256) void k_outg(const float* __restrict__ fpre, const float* __restrict__ Wo,
                                              const float* __restrict__ z, const int* __restrict__ hi,
                                              const int* __restrict__ lo, const int* __restrict__ labels,
                                              float* __restrict__ out){
  int bo = blockIdx.x, t = threadIdx.x;
  __shared__ float rowv[E_];
  __shared__ float vb[B_];
  __shared__ int cb[B_];
  __shared__ float gsh;
  rowv[t] = fpre[(size_t)bo*E_ + t];
  rowv[t + 256] = fpre[(size_t)bo*E_ + t + 256];
  if (t < B_){ vb[t] = 0.f; cb[t] = 0; }
  __syncthreads();
  for (int p = t; p < B_*O_; p += 256){
    int b = p / O_;
    if (labels[p] != 0){
      float acc = 0.f;
      for (int tt = 0; tt < T_; ++tt){
        float shi = z[hi[p*T_ + tt]];
        float slo = z[lo[p*T_ + tt]];
        acc += (1.f - __powf(shi + 1e-7f, 0.7f)) / 0.7f;
        acc += (1.f - __powf(1.f - slo + 1e-7f, 0.7f)) / 0.7f;
      }
      atomicAdd(&vb[b], acc / (float)T_);
      atomicAdd(&cb[b], 1);
    }
  }
  __syncthreads();
  if (t == 0){
    float g = 0.f;
    for (int b = 0; b < B_; ++b) g += vb[b] / fmaxf((float)cb[b], 1.f);
    gsh = 0.5f * (g / (float)B_);
  }
  __syncthreads();
  float g = gsh;
  float a0 = 0.f, a1 = 0.f;
  for (int ep = 0; ep < E_; ++ep){
    float r = rowv[ep];
    a0 += r * Wo[(size_t)ep*E_ + t];
    a1 += r * Wo[(size_t)ep*E_ + t + 256];
  }
  out[(size_t)bo*E_ + t] = a0 + g;
  out[(size_t)bo*E_ + t + 256] = a1 + g;
}

extern "C" void kernel_launch(void* const* d_in, const int* in_sizes, int n_in,
                              void* d_out, int out_size, void* d_ws, size_t ws_size,
                              hipStream_t stream) {
  (void)in_sizes; (void)n_in; (void)out_size; (void)ws_size;
  const float* F    = (const float*)d_in[0];
  const int*   labels = (const int*)d_in[1];
  const float* TMm  = (const float*)d_in[2];
  const float* entW = (const float*)d_in[3];
  const float* entB = (const float*)d_in[4];
  const float* Wq   = (const float*)d_in[5];
  const float* Wk   = (const float*)d_in[6];
  const float* Wv   = (const float*)d_in[7];
  const float* Wo   = (const float*)d_in[8];
  const float* W1   = (const float*)d_in[9];
  const float* b1   = (const float*)d_in[10];
  const float* W2   = (const float*)d_in[11];
  const float* b2   = (const float*)d_in[12];
  float* out = (float*)d_out;

  size_t off = 0;
  char* wsb = (char*)d_ws;
  auto alloc = [&](size_t bytes) -> char* {
    char* p = wsb + off; off += (bytes + 255) & ~(size_t)255; return p;
  };
  unsigned short* A_kv = (unsigned short*)alloc((size_t)MPAD * D_ * 2);
  unsigned short* Wall = (unsigned short*)alloc((size_t)NW * D_ * 2);
  float* umax          = (float*)alloc((size_t)TM_ * D_ * 4);
  char*  c2reg         = alloc((size_t)MPAD * NW * 4);      // overlay region (51.9 MB)
  float* C2    = (float*)c2reg;
  unsigned short* wnorm = (unsigned short*)c2reg;           // 15,728,640 B
  float* simp  = (float*)(c2reg + 15728640);                // 31,457,280 B (8 partials) -> ends 47.2 MB
  unsigned short* ubf = (unsigned short*)alloc((size_t)MSIM * D_ * 2);
  float* rmaxr = (float*)alloc((size_t)400 * D_ * 4);
  float* qbuf  = (float*)alloc((size_t)B_ * O_ * E_ * 4);
  float* fpre  = (float*)alloc((size_t)B_ * O_ * E_ * 4);
  float* rmsum = (float*)alloc(400 * 4);
  float* msum  = (float*)alloc(TM_ * 4);
  int*   hib   = (int*)alloc(6400 * 4);
  int*   lob   = (int*)alloc(6400 * 4);
  float* zbuf  = (float*)alloc((size_t)MROWS * 4);

  // fused preprocessing: mempool | region | weight-transpose | q
  k_pre<<<8896, 256, 0, stream>>>(F, TMm, Wk, Wv, W1, Wall, A_kv, rmaxr, rmsum, ubf,
                                  umax, msum, wnorm, labels, entW, entB, Wq, qbuf);
  // sim GEMM, split-K=8 -> partials
  k_gemm<<<(MSIM/128)*(NSIM/128)*SIMK, 256, 0, stream>>>(ubf, wnorm, simp, NSIM/128, NSIM, 0, 60,
                                                         (MSIM/128)*(NSIM/128), (D_/64)/SIMK,
                                                         (size_t)MSIM*NSIM);
  // fused reduce+prune+rescore+gather (grid pads A_kv)
  k_pick<<<448, 256, 0, stream>>>(simp, rmaxr, rmsum, umax, msum, A_kv);
  // mega GEMM: [k|v|h1] for all kv rows (overwrites overlay region)
  k_gemm<<<(MPAD/128)*(NW/128), 256, 0, stream>>>(A_kv, Wall, C2, NW/128, NW, 1,
                                                  (MPAD/128)*(NW/128),
                                                  (MPAD/128)*(NW/128), D_/64, 0);
  // fused post: attention | hi/lo | z-MLP
  k_post<<<2560, 256, 0, stream>>>(qbuf, C2, fpre, hib, lob, b1, W2, b2, zbuf);
  // out = fpre @ Wo + beta*gce
  k_outg<<<B_*O_, 256, 0, stream>>>(fpre, Wo, zbuf, hib, lob, labels, out);
}

// Round 4
// 501.942 us; speedup vs baseline: 1.3847x; 1.0175x over previous
//
#include <hip/hip_runtime.h>

#define B_   20
#define T_   20
#define RN   20
#define D_   4096
#define O_   16
#define E_   512
#define H_   8
#define DH   64
#define TM_  1900
#define NKV  420          // per-batch kv rows: 400 region + 20 mem
#define MROWS (B_*NKV)    // 8400
#define MPAD 8448         // 33 * 256
#define NW   1536         // Wk|Wv|W1 output channels
#define NSIM 1920         // 15 * 128 (TM padded)
#define MSIM 512          // 4 * 128 (B*T padded)
#define CAP  256
#define SIMK 8            // split-K factor for sim GEMM

using f32x4  = __attribute__((ext_vector_type(4))) float;
using bf16x8 = __attribute__((ext_vector_type(8))) __bf16;

__device__ __forceinline__ unsigned short f2bf(float f){
  unsigned u = __float_as_uint(f);
  u += 0x7fffu + ((u >> 16) & 1u);
  return (unsigned short)(u >> 16);
}

__device__ __forceinline__ void st_bf4(unsigned short* dst, float4 v){
  ushort4 o = make_ushort4(f2bf(v.x), f2bf(v.y), f2bf(v.z), f2bf(v.w));
  *(ushort4*)dst = o;
}

__device__ __forceinline__ float bsum256(float v, float* sh){
  int t = threadIdx.x;
  for (int o = 32; o; o >>= 1) v += __shfl_down(v, o, 64);
  __syncthreads();
  if ((t & 63) == 0) sh[t >> 6] = v;
  __syncthreads();
  return sh[0] + sh[1] + sh[2] + sh[3];
}

__device__ __forceinline__ float bmax256(float v, float* sh){
  int t = threadIdx.x;
  for (int o = 32; o; o >>= 1) v = fmaxf(v, __shfl_down(v, o, 64));
  __syncthreads();
  if ((t & 63) == 0) sh[t >> 6] = v;
  __syncthreads();
  return fmaxf(fmaxf(sh[0], sh[1]), fmaxf(sh[2], sh[3]));
}

__device__ __forceinline__ void gld16(const void* g, void* l){
  __builtin_amdgcn_global_load_lds(
      (const __attribute__((address_space(1))) unsigned int*)g,
      (__attribute__((address_space(3))) unsigned int*)l, 16, 0, 0);
}

// ================= fused preprocessing (horizontal fusion) =================
// blocks [0,1920): temporal-mem max-pool -> umax/msum/wnorm (+pad)
// blocks [1920,2432): region pass -> A_kv, rmaxr, rmsum, ubf (+pad)
// blocks [2432,8576): weight transpose+convert -> Wall
// blocks [8576,8896): q = (onehot@entity_W + b) @ Wq
__global__ __launch_bounds__(256) void k_pre(
    const float* __restrict__ F, const float* __restrict__ TMm,
    const float* __restrict__ Wk, const float* __restrict__ Wv, const float* __restrict__ W1,
    unsigned short* __restrict__ Wall,
    unsigned short* __restrict__ A, float* __restrict__ rmaxr, float* __restrict__ rmsum,
    unsigned short* __restrict__ ubf,
    float* __restrict__ umax, float* __restrict__ msum, unsigned short* __restrict__ wnorm,
    const int* __restrict__ labels, const float* __restrict__ entW, const float* __restrict__ entB,
    const float* __restrict__ Wq, float* __restrict__ q){
  __shared__ char smem[4352];
  int bid = blockIdx.x, t = threadIdx.x;
  if (bid < 1920){
    // ---- temporal-mem frame max-pool ----
    int m = bid;
    if (m >= TM_){
      int4 zz = make_int4(0,0,0,0);
      int4* row = (int4*)(wnorm + (size_t)m*D_);
      row[t] = zz; row[t + 256] = zz;
      return;
    }
    float* sh = (float*)smem;
    const float* base = TMm + (size_t)m*T_*D_;
    float4 mx[4];
#pragma unroll
    for (int i = 0; i < 4; ++i) mx[i] = make_float4(-1e30f,-1e30f,-1e30f,-1e30f);
    for (int f = 0; f < T_; ++f){
#pragma unroll
      for (int i = 0; i < 4; ++i){
        float4 v = *(const float4*)(base + (size_t)f*D_ + i*1024 + t*4);
        mx[i].x = fmaxf(mx[i].x, v.x); mx[i].y = fmaxf(mx[i].y, v.y);
        mx[i].z = fmaxf(mx[i].z, v.z); mx[i].w = fmaxf(mx[i].w, v.w);
      }
    }
    float s = 0.f;
#pragma unroll
    for (int i = 0; i < 4; ++i){
      *(float4*)(umax + (size_t)m*D_ + i*1024 + t*4) = mx[i];
      s += mx[i].x*mx[i].x + mx[i].y*mx[i].y + mx[i].z*mx[i].z + mx[i].w*mx[i].w;
    }
    s = bsum256(s, sh);
    if (t == 0) msum[m] = s;
    float inv = 1.f / fmaxf(sqrtf(s), 1e-12f);
#pragma unroll
    for (int i = 0; i < 4; ++i){
      float4 u = mx[i];
      u.x *= inv; u.y *= inv; u.z *= inv; u.w *= inv;
      st_bf4(wnorm + (size_t)m*D_ + i*1024 + t*4, u);
    }
  } else if (bid < 2432){
    // ---- region pass: l2norm rows -> A_kv(bf16), region max -> rmaxr/rmsum/ubf ----
    int bt = bid - 1920;
    if (bt >= 400){
      int4 zz = make_int4(0,0,0,0);
      int4* row = (int4*)(ubf + (size_t)bt*D_);
      row[t] = zz; row[t + 256] = zz;
      return;
    }
    float* sh = (float*)smem;
    int b = bt / T_, tt = bt % T_;
    const float* fb = F + (size_t)bt*RN*D_;
    unsigned short* ab = A + ((size_t)b*NKV + (size_t)tt*RN)*D_;
    float4 mx[4];
#pragma unroll
    for (int i = 0; i < 4; ++i) mx[i] = make_float4(-1e30f,-1e30f,-1e30f,-1e30f);
    for (int r = 0; r < RN; ++r){
      float4 v[4];
      float s = 0.f;
#pragma unroll
      for (int i = 0; i < 4; ++i){
        v[i] = *(const float4*)(fb + (size_t)r*D_ + i*1024 + t*4);
        s += v[i].x*v[i].x + v[i].y*v[i].y + v[i].z*v[i].z + v[i].w*v[i].w;
      }
      s = bsum256(s, sh);
      float ri = 1.f / fmaxf(sqrtf(s), 1e-12f);
#pragma unroll
      for (int i = 0; i < 4; ++i){
        v[i].x *= ri; v[i].y *= ri; v[i].z *= ri; v[i].w *= ri;
        st_bf4(ab + (size_t)r*D_ + i*1024 + t*4, v[i]);
        mx[i].x = fmaxf(mx[i].x, v[i].x); mx[i].y = fmaxf(mx[i].y, v[i].y);
        mx[i].z = fmaxf(mx[i].z, v[i].z); mx[i].w = fmaxf(mx[i].w, v[i].w);
      }
    }
    float s2 = 0.f;
#pragma unroll
    for (int i = 0; i < 4; ++i){
      *(float4*)(rmaxr + (size_t)bt*D_ + i*1024 + t*4) = mx[i];
      s2 += mx[i].x*mx[i].x + mx[i].y*mx[i].y + mx[i].z*mx[i].z + mx[i].w*mx[i].w;
    }
    s2 = bsum256(s2, sh);
    if (t == 0) rmsum[bt] = s2;
    float inv = 1.f / fmaxf(sqrtf(s2), 1e-12f);
#pragma unroll
    for (int i = 0; i < 4; ++i){
      float4 u = mx[i];
      u.x *= inv; u.y *= inv; u.z *= inv; u.w *= inv;
      st_bf4(ubf + (size_t)bt*D_ + i*1024 + t*4, u);
    }
  } else if (bid < 8576){
    // ---- weight transpose+convert: Wall[n][k] = bf16(src[k][n]) ----
    int wti = bid - 2432;
    float* tile = (float*)smem;          // [32][33]
    int kb = (wti & 127) * 32, nb = (wti >> 7) * 32;
    const float* src; int nc0;
    if (nb < 512)      { src = Wk; nc0 = nb; }
    else if (nb < 1024){ src = Wv; nc0 = nb - 512; }
    else               { src = W1; nc0 = nb - 1024; }
    int tx = t & 31, ty = t >> 5;
#pragma unroll
    for (int j = 0; j < 4; ++j){
      int k = kb + ty + j*8;
      tile[(ty + j*8)*33 + tx] = src[(size_t)k*E_ + nc0 + tx];
    }
    __syncthreads();
#pragma unroll
    for (int j = 0; j < 4; ++j){
      int n = nb + ty + j*8;
      int k = kb + tx;
      Wall[(size_t)n*D_ + k] = f2bf(tile[tx*33 + ty + j*8]);
    }
  } else {
    // ---- q = (onehot@entity_W + entity_b) @ Wq ----
    int bo = bid - 8576;
    float* qe = (float*)smem;
    int lab = labels[bo];
    float sel = (lab != 0) ? 1.f : 0.f;
    qe[t]       = sel * entW[(size_t)lab*E_ + t]       + entB[t];
    qe[t + 256] = sel * entW[(size_t)lab*E_ + t + 256] + entB[t + 256];
    __syncthreads();
    float a0 = 0.f, a1 = 0.f;
    for (int ep = 0; ep < E_; ++ep){
      float r = qe[ep];
      a0 += r * Wq[(size_t)ep*E_ + t];
      a1 += r * Wq[(size_t)ep*E_ + t + 256];
    }
    q[(size_t)bo*E_ + t] = a0;
    q[(size_t)bo*E_ + t + 256] = a1;
  }
}

// ---------- 128x128 bf16 MFMA GEMM with split-K (used for the sim GEMM) ----------
__global__ __launch_bounds__(256, 2) void k_gemm(const unsigned short* __restrict__ A,
                                                 const unsigned short* __restrict__ Bw,
                                                 float* __restrict__ C,
                                                 int nNt, int ldc, int doswz, int nwg,
                                                 int nblk, int nkt, size_t cpart){
  __shared__ char lds[32768];
  int part = blockIdx.x / nblk;
  int bid  = blockIdx.x % nblk;
  if (doswz){ int q = nwg >> 3; bid = (bid & 7)*q + (bid >> 3); }
  int mt = bid / nNt, nt = bid % nNt;
  int tid = threadIdx.x, wv = tid >> 6, l = tid & 63;
  int wr = (wv >> 1) * 64, wc = (wv & 1) * 64;
  const char* Ab = (const char*)A + (size_t)mt*128*(size_t)(D_*2);
  const char* Bb = (const char*)Bw + (size_t)nt*128*(size_t)(D_*2);
  C += (size_t)part * cpart;
  f32x4 acc[4][4];
#pragma unroll
  for (int m = 0; m < 4; ++m)
#pragma unroll
    for (int n = 0; n < 4; ++n) acc[m][n] = (f32x4){0.f,0.f,0.f,0.f};
  int kt0 = part * nkt;
  for (int kt = kt0; kt < kt0 + nkt; ++kt){
    int ktoff = kt*128;
#pragma unroll
    for (int i = 0; i < 4; ++i){
      int idx = i*256 + tid;
      int row = idx >> 3, u = idx & 7;
      int ul = u ^ (row & 7);   // pre-swizzled global source (G21)
      gld16(Ab + (size_t)row*(D_*2) + ktoff + ul*16, lds + i*4096 + wv*1024);
      gld16(Bb + (size_t)row*(D_*2) + ktoff + ul*16, lds + 16384 + i*4096 + wv*1024);
    }
    __syncthreads();
#pragma unroll
    for (int kk = 0; kk < 2; ++kk){
      bf16x8 av[4], bv[4];
#pragma unroll
      for (int m = 0; m < 4; ++m){
        int row = wr + m*16 + (l & 15);
        int u = (kk*4 + (l >> 4)) ^ (row & 7);
        av[m] = *(const bf16x8*)(lds + row*128 + u*16);
      }
#pragma unroll
      for (int n = 0; n < 4; ++n){
        int row = wc + n*16 + (l & 15);
        int u = (kk*4 + (l >> 4)) ^ (row & 7);
        bv[n] = *(const bf16x8*)(lds + 16384 + row*128 + u*16);
      }
#pragma unroll
      for (int m = 0; m < 4; ++m)
#pragma unroll
        for (int n = 0; n < 4; ++n)
          acc[m][n] = __builtin_amdgcn_mfma_f32_16x16x32_bf16(av[m], bv[n], acc[m][n], 0, 0, 0);
    }
    __syncthreads();
  }
  int rq = (l >> 4) * 4, cq = l & 15;
  size_t crow0 = (size_t)mt*128 + wr, ccol0 = (size_t)nt*128 + wc;
#pragma unroll
  for (int m = 0; m < 4; ++m)
#pragma unroll
    for (int n = 0; n < 4; ++n){
      size_t r0 = crow0 + m*16 + rq, c0 = ccol0 + n*16 + cq;
#pragma unroll
      for (int j = 0; j < 4; ++j)
        C[(r0 + j)*ldc + c0] = acc[m][n][j];
    }
}

// ---------- 256x256 bf16 MFMA GEMM, BK=64, 8 waves, double-buffered prefetch ----------
// One barrier per K-tile; stage of kt+1 issued before kt's 64-MFMA block so HBM
// latency hides under compute and the barrier's vmcnt(0) drain is cheap (T3-min).
__global__ __launch_bounds__(512, 1) void k_gemm256(const unsigned short* __restrict__ A,
                                                    const unsigned short* __restrict__ Bw,
                                                    float* __restrict__ C,
                                                    int nNt, int ldc, int nwg){
  __shared__ char lds[131072];   // buf c at c*65536: A[256][64] @ +0, B[256][64] @ +32768
  int bid = blockIdx.x;
  { // bijective XCD swizzle (m204)
    int q8 = nwg >> 3, r8 = nwg & 7, x = bid & 7, s = bid >> 3;
    bid = (x < r8 ? x*(q8+1) : r8*(q8+1) + (x-r8)*q8) + s;
  }
  int mt = bid / nNt, nt = bid % nNt;
  int tid = threadIdx.x, wid = tid >> 6, l = tid & 63;
  int wr = (wid >> 2) * 128;     // wave M offset (2 waves in M)
  int wc = (wid & 3) * 64;       // wave N offset (4 waves in N)
  int fr = l & 15, fq = l >> 4;
  const char* Ab = (const char*)A + (size_t)mt*256*(size_t)(D_*2);
  const char* Bb = (const char*)Bw + (size_t)nt*256*(size_t)(D_*2);
  f32x4 acc[8][4];
#pragma unroll
  for (int m = 0; m < 8; ++m)
#pragma unroll
    for (int n = 0; n < 4; ++n) acc[m][n] = (f32x4){0.f,0.f,0.f,0.f};

  // stage K-tile 0 into buf 0
#pragma unroll
  for (int i = 0; i < 4; ++i){
    int idx = i*512 + tid;
    int row = idx >> 3, u = idx & 7;
    int ul = u ^ (row & 7);
    gld16(Ab + (size_t)row*(D_*2) + (size_t)(ul*16), lds + idx*16);
    gld16(Bb + (size_t)row*(D_*2) + (size_t)(ul*16), lds + 32768 + idx*16);
  }
  __syncthreads();

  int c = 0;
  for (int kt = 0; kt < D_/64; ++kt){
    if (kt < D_/64 - 1){            // issue next-tile staging into the idle buffer
      int ktoff = (kt + 1) * 128;
      char* dA = lds + (c^1)*65536;
      char* dB = dA + 32768;
#pragma unroll
      for (int i = 0; i < 4; ++i){
        int idx = i*512 + tid;
        int row = idx >> 3, u = idx & 7;
        int ul = u ^ (row & 7);
        gld16(Ab + (size_t)row*(D_*2) + ktoff + ul*16, dA + idx*16);
        gld16(Bb + (size_t)row*(D_*2) + ktoff + ul*16, dB + idx*16);
      }
    }
    const char* LA = lds + c*65536;
    const char* LB = LA + 32768;
    bf16x8 bv[4][2];
#pragma unroll
    for (int n = 0; n < 4; ++n)
#pragma unroll
      for (int kk = 0; kk < 2; ++kk){
        int row = wc + n*16 + fr;
        int u = (kk*4 + fq) ^ (row & 7);
        bv[n][kk] = *(const bf16x8*)(LB + row*128 + u*16);
      }
    __builtin_amdgcn_s_setprio(1);
#pragma unroll
    for (int mp = 0; mp < 4; ++mp){
      bf16x8 av[2][2];
#pragma unroll
      for (int mm = 0; mm < 2; ++mm)
#pragma unroll
        for (int kk = 0; kk < 2; ++kk){
          int row = wr + (mp*2 + mm)*16 + fr;
          int u = (kk*4 + fq) ^ (row & 7);
          av[mm][kk] = *(const bf16x8*)(LA + row*128 + u*16);
        }
#pragma unroll
      for (int mm = 0; mm < 2; ++mm)
#pragma unroll
        for (int n = 0; n < 4; ++n)
#pragma unroll
          for (int kk = 0; kk < 2; ++kk)
            acc[mp*2 + mm][n] = __builtin_amdgcn_mfma_f32_16x16x32_bf16(
                av[mm][kk], bv[n][kk], acc[mp*2 + mm][n], 0, 0, 0);
    }
    __builtin_amdgcn_s_setprio(0);
    __syncthreads();               // drains vmcnt(0): prefetch latency already covered
    c ^= 1;
  }
  size_t crow0 = (size_t)mt*256 + wr, ccol0 = (size_t)nt*256 + wc;
#pragma unroll
  for (int m = 0; m < 8; ++m)
#pragma unroll
    for (int n = 0; n < 4; ++n){
      size_t r0 = crow0 + m*16 + fq*4, c0 = ccol0 + n*16 + fr;
#pragma unroll
      for (int j = 0; j < 4; ++j)
        C[(r0 + j)*ldc + c0] = acc[m][n][j];
    }
}

// ---------- fused: sum split-K partials, margin-prune, fp32 rescore, gather mem row ----------
__global__ __launch_bounds__(256) void k_pick(const float* __restrict__ simp,
                                              const float* __restrict__ rmaxr, const float* __restrict__ rmsum,
                                              const float* __restrict__ umax, const float* __restrict__ msum,
                                              unsigned short* __restrict__ A){
  int bt = blockIdx.x, t = threadIdx.x;
  if (bt >= 400){   // zero A_kv pad rows 8400..8447
    int4 z = make_int4(0,0,0,0);
    int4* row = (int4*)(A + (size_t)(MROWS + bt - 400)*D_);
    row[t] = z; row[t + 256] = z;
    return;
  }
  __shared__ float srow[NSIM];
  __shared__ float sh[4];
  __shared__ int cnt;
  __shared__ int cl[CAP];
  for (int m = t; m < NSIM; m += 256){
    float s = 0.f;
#pragma unroll
    for (int p = 0; p < SIMK; ++p)
      s += simp[(size_t)p*MSIM*NSIM + (size_t)bt*NSIM + m];
    srow[m] = s;
  }
  if (t == 0) cnt = 0;
  __syncthreads();
  float mx = -1e30f;
  for (int m = t; m < TM_; m += 256) mx = fmaxf(mx, srow[m]);
  mx = bmax256(mx, sh);
  float thr = mx - 2.5e-4f;
  for (int m = t; m < TM_; m += 256){
    if (srow[m] >= thr){
      int p = atomicAdd(&cnt, 1);
      if (p < CAP) cl[p] = m;
    }
  }
  __syncthreads();
  int cn = cnt < CAP ? cnt : CAP;
  // fp32 rescore, total-order tie-break -> deterministic exact argmax
  float rinvv = 1.f / fmaxf(sqrtf(rmsum[bt]), 1e-12f);
  const float* a = rmaxr + (size_t)bt*D_;
  float best = -1e30f; int bestm = 0x7fffffff;
  for (int ci = 0; ci < cn; ++ci){
    int m = cl[ci];
    const float* wrow = umax + (size_t)m*D_;
    float p = 0.f;
    for (int i = t*4; i < D_; i += 1024){
      float4 av = *(const float4*)(a + i);
      float4 wv = *(const float4*)(wrow + i);
      p += av.x*wv.x + av.y*wv.y + av.z*wv.z + av.w*wv.w;
    }
    p = bsum256(p, sh);
    float sim = p * rinvv * (1.f / fmaxf(sqrtf(msum[m]), 1e-12f));
    if (sim > best || (sim == best && m < bestm)){ best = sim; bestm = m; }
  }
  // gather retrieved memory row -> A_kv (bf16, unnormalized max-pool)
  int b = bt / T_, tt = bt % T_;
  unsigned short* dst = A + ((size_t)b*NKV + 400 + tt)*D_;
  const float* src = umax + (size_t)bestm*D_;
#pragma unroll
  for (int i = 0; i < 4; ++i){
    size_t off = (size_t)i*1024 + t*4;
    float4 v = *(const float4*)(src + off);
    st_bf4(dst + off, v);
  }
}

// ================= fused post-GEMM (horizontal fusion) =================
__global__ __launch_bounds__(256) void k_post(const float* __restrict__ q, const float* __restrict__ c2,
                                              float* __restrict__ fpre, int* __restrict__ hi,
                                              int* __restrict__ lo, const float* __restrict__ b1,
                                              const float* __restrict__ W2, const float* __restrict__ b2,
                                              float* __restrict__ z){
  __shared__ char smem[58368];
  int bid = blockIdx.x, t = threadIdx.x;
  if (bid < 160){
    // ---- attention ----
    int b = bid >> 3, h = bid & 7;
    int w = t >> 6, l = t & 63;
    float* qhp = (float*)smem;               // [16][65]
    float* kb  = (float*)(smem + 4160);      // [105][65]
    float* sc  = (float*)(smem + 31460);     // [16][420]
    for (int i = t; i < O_*DH; i += 256){
      int o = i >> 6, d = i & 63;
      qhp[o*65 + d] = q[((size_t)(b*O_ + o))*E_ + h*DH + d] * 0.125f;
    }
    __syncthreads();
    for (int c = 0; c < 4; ++c){
      for (int i = t; i < 105*DH; i += 256){
        int j = i >> 6, d = i & 63;
        kb[j*65 + d] = c2[((size_t)(b*NKV + c*105 + j))*NW + h*DH + d];
      }
      __syncthreads();
      for (int i = t; i < O_*105; i += 256){
        int o = i / 105, j = i % 105;
        float acc = 0.f;
        for (int d = 0; d < DH; ++d) acc += qhp[o*65 + d] * kb[j*65 + d];
        sc[o*420 + c*105 + j] = acc;
      }
      __syncthreads();
    }
    for (int oi = 0; oi < 4; ++oi){
      int o = w + oi*4;
      float mx = -1e30f;
      for (int n = l; n < NKV; n += 64) mx = fmaxf(mx, sc[o*420 + n]);
      for (int of = 32; of; of >>= 1) mx = fmaxf(mx, __shfl_xor(mx, of, 64));
      float sum = 0.f;
      for (int n = l; n < NKV; n += 64){ float e = expf(sc[o*420 + n] - mx); sc[o*420 + n] = e; sum += e; }
      for (int of = 32; of; of >>= 1) sum += __shfl_xor(sum, of, 64);
      float inv = 1.f / sum;
      for (int n = l; n < NKV; n += 64) sc[o*420 + n] *= inv;
    }
    __syncthreads();
    float acc[4] = {0.f, 0.f, 0.f, 0.f};
    for (int c = 0; c < 4; ++c){
      for (int i = t; i < 105*DH; i += 256){
        int j = i >> 6, d = i & 63;
        kb[j*65 + d] = c2[((size_t)(b*NKV + c*105 + j))*NW + E_ + h*DH + d];
      }
      __syncthreads();
#pragma unroll
      for (int og = 0; og < 4; ++og){
        int o = og*4 + w;
        float a = 0.f;
        for (int j = 0; j < 105; ++j) a += sc[o*420 + c*105 + j] * kb[j*65 + l];
        acc[og] += a;
      }
      __syncthreads();
    }
#pragma unroll
    for (int og = 0; og < 4; ++og){
      int o = og*4 + w;
      fpre[((size_t)(b*O_ + o))*E_ + h*DH + l] = acc[og];
    }
  } else if (bid < 560){
    // ---- hi/lo region selection ----
    int bt = bid - 160;
    int b = bt / T_, tt = bt % T_;
    float* kl = (float*)smem;                // [20][513]
    float* qr = (float*)(smem + 41040);      // [16][20]
    for (int i = t; i < RN*E_; i += 256){
      int r = i >> 9, e = i & 511;
      kl[r*513 + e] = c2[((size_t)(b*NKV + tt*RN + r))*NW + e];
    }
    __syncthreads();
#pragma unroll
    for (int pp = 0; pp < 2; ++pp){
      int p = t + pp*256;
      if (p < O_*RN){
        int o = p / RN, r = p % RN;
        const float* qrow = q + ((size_t)(b*O_ + o))*E_;
        float acc = 0.f;
        for (int e = 0; e < E_; ++e) acc += qrow[e] * kl[r*513 + e];
        qr[o*20 + r] = acc;
      }
    }
    __syncthreads();
    if (t < O_){
      int o = t;
      float bh = qr[o*20], bl = qr[o*20]; int ih = 0, il = 0;
#pragma unroll
      for (int r = 1; r < RN; ++r){
        float v = qr[o*20 + r];
        if (v > bh){ bh = v; ih = r; }
        if (v < bl){ bl = v; il = r; }
      }
      int rowbase = b*NKV + tt*RN;
      int outi = (b*O_ + o)*T_ + tt;
      hi[outi] = rowbase + ih;
      lo[outi] = rowbase + il;
    }
  } else {
    // ---- z = sigmoid(tanh(h1+b1)@W2 + b2), region rows only ----
    int g = (bid - 560)*4 + (t >> 6);
    int l = t & 63;
    int b = g / 400, j = g % 400;
    int row = b*NKV + j;
    const float* hrow = c2 + (size_t)row*NW + 1024;
    float acc = 0.f;
    for (int e = l; e < E_; e += 64) acc += tanhf(hrow[e] + b1[e]) * W2[e];
    for (int of = 32; of; of >>= 1) acc += __shfl_down(acc, of, 64);
    if (l == 0) z[row] = 1.f / (1.f + expf(-(acc + b2[0])));
  }
}

// ---------- out = fpre @ Wo + beta*gce (gce recomputed per block) ----------
__global__ __launch_bounds__(256) void k_outg(const float* __restrict__ fpre, const float* __restrict__ Wo,
                                              const float* __restrict__ z, const int* __restrict__ hi,
                                              const int* __restrict__ lo, const int* __restrict__ labels,
                                              float* __restrict__ out){
  int bo = blockIdx.x, t = threadIdx.x;
  __shared__ float rowv[E_];
  __shared__ float vb[B_];
  __shared__ int cb[B_];
  __shared__ float gsh;
  rowv[t] = fpre[(size_t)bo*E_ + t];
  rowv[t + 256] = fpre[(size_t)bo*E_ + t + 256];
  if (t < B_){ vb[t] = 0.f; cb[t] = 0; }
  __syncthreads();
  for (int p = t; p < B_*O_; p += 256){
    int b = p / O_;
    if (labels[p] != 0){
      float acc = 0.f;
      for (int tt = 0; tt < T_; ++tt){
        float shi = z[hi[p*T_ + tt]];
        float slo = z[lo[p*T_ + tt]];
        acc += (1.f - __powf(shi + 1e-7f, 0.7f)) / 0.7f;
        acc += (1.f - __powf(1.f - slo + 1e-7f, 0.7f)) / 0.7f;
      }
      atomicAdd(&vb[b], acc / (float)T_);
      atomicAdd(&cb[b], 1);
    }
  }
  __syncthreads();
  if (t == 0){
    float g = 0.f;
    for (int b = 0; b < B_; ++b) g += vb[b] / fmaxf((float)cb[b], 1.f);
    gsh = 0.5f * (g / (float)B_);
  }
  __syncthreads();
  float g = gsh;
  float a0 = 0.f, a1 = 0.f;
  for (int ep = 0; ep < E_; ++ep){
    float r = rowv[ep];
    a0 += r * Wo[(size_t)ep*E_ + t];
    a1 += r * Wo[(size_t)ep*E_ + t + 256];
  }
  out[(size_t)bo*E_ + t] = a0 + g;
  out[(size_t)bo*E_ + t + 256] = a1 + g;
}

extern "C" void kernel_launch(void* const* d_in, const int* in_sizes, int n_in,
                              void* d_out, int out_size, void* d_ws, size_t ws_size,
                              hipStream_t stream) {
  (void)in_sizes; (void)n_in; (void)out_size; (void)ws_size;
  const float* F    = (const float*)d_in[0];
  const int*   labels = (const int*)d_in[1];
  const float* TMm  = (const float*)d_in[2];
  const float* entW = (const float*)d_in[3];
  const float* entB = (const float*)d_in[4];
  const float* Wq   = (const float*)d_in[5];
  const float* Wk   = (const float*)d_in[6];
  const float* Wv   = (const float*)d_in[7];
  const float* Wo   = (const float*)d_in[8];
  const float* W1   = (const float*)d_in[9];
  const float* b1   = (const float*)d_in[10];
  const float* W2   = (const float*)d_in[11];
  const float* b2   = (const float*)d_in[12];
  float* out = (float*)d_out;

  size_t off = 0;
  char* wsb = (char*)d_ws;
  auto alloc = [&](size_t bytes) -> char* {
    char* p = wsb + off; off += (bytes + 255) & ~(size_t)255; return p;
  };
  unsigned short* A_kv = (unsigned short*)alloc((size_t)MPAD * D_ * 2);
  unsigned short* Wall = (unsigned short*)alloc((size_t)NW * D_ * 2);
  float* umax          = (float*)alloc((size_t)TM_ * D_ * 4);
  char*  c2reg         = alloc((size_t)MPAD * NW * 4);      // overlay region (51.9 MB)
  float* C2    = (float*)c2reg;
  unsigned short* wnorm = (unsigned short*)c2reg;           // 15,728,640 B
  float* simp  = (float*)(c2reg + 15728640);                // 31,457,280 B (8 partials) -> ends 47.2 MB
  unsigned short* ubf = (unsigned short*)alloc((size_t)MSIM * D_ * 2);
  float* rmaxr = (float*)alloc((size_t)400 * D_ * 4);
  float* qbuf  = (float*)alloc((size_t)B_ * O_ * E_ * 4);
  float* fpre  = (float*)alloc((size_t)B_ * O_ * E_ * 4);
  float* rmsum = (float*)alloc(400 * 4);
  float* msum  = (float*)alloc(TM_ * 4);
  int*   hib   = (int*)alloc(6400 * 4);
  int*   lob   = (int*)alloc(6400 * 4);
  float* zbuf  = (float*)alloc((size_t)MROWS * 4);

  // fused preprocessing: mempool | region | weight-transpose | q
  k_pre<<<8896, 256, 0, stream>>>(F, TMm, Wk, Wv, W1, Wall, A_kv, rmaxr, rmsum, ubf,
                                  umax, msum, wnorm, labels, entW, entB, Wq, qbuf);
  // sim GEMM, split-K=8 -> partials (128-tile kernel)
  k_gemm<<<(MSIM/128)*(NSIM/128)*SIMK, 256, 0, stream>>>(ubf, wnorm, simp, NSIM/128, NSIM, 0, 60,
                                                         (MSIM/128)*(NSIM/128), (D_/64)/SIMK,
                                                         (size_t)MSIM*NSIM);
  // fused reduce+prune+rescore+gather (grid pads A_kv)
  k_pick<<<448, 256, 0, stream>>>(simp, rmaxr, rmsum, umax, msum, A_kv);
  // mega GEMM: 256x256 double-buffered prefetch kernel
  k_gemm256<<<(MPAD/256)*(NW/256), 512, 0, stream>>>(A_kv, Wall, C2, NW/256, NW,
                                                     (MPAD/256)*(NW/256));
  // fused post: attention | hi/lo | z-MLP
  k_post<<<2560, 256, 0, stream>>>(qbuf, C2, fpre, hib, lob, b1, W2, b2, zbuf);
  // out = fpre @ Wo + beta*gce
  k_outg<<<B_*O_, 256, 0, stream>>>(fpre, Wo, zbuf, hib, lob, labels, out);
}

// Round 5
// 485.859 us; speedup vs baseline: 1.4306x; 1.0331x over previous
//
#include <hip/hip_runtime.h>

#define B_   20
#define T_   20
#define RN   20
#define D_   4096
#define O_   16
#define E_   512
#define H_   8
#define DH   64
#define TM_  1900
#define MREG 8192         // region rows padded to 32*256
#define NW   1536         // Wk|Wv|W1 output channels
#define NSIM 2048         // TM padded to 8*256
#define MSIM 512          // B*T padded to 2*256
#define CAP  256

using f32x4  = __attribute__((ext_vector_type(4))) float;
using bf16x8 = __attribute__((ext_vector_type(8))) __bf16;

__device__ __forceinline__ unsigned short f2bf(float f){
  unsigned u = __float_as_uint(f);
  u += 0x7fffu + ((u >> 16) & 1u);
  return (unsigned short)(u >> 16);
}

__device__ __forceinline__ void st_bf4(unsigned short* dst, float4 v){
  ushort4 o = make_ushort4(f2bf(v.x), f2bf(v.y), f2bf(v.z), f2bf(v.w));
  *(ushort4*)dst = o;
}

__device__ __forceinline__ float bsum256(float v, float* sh){
  int t = threadIdx.x;
  for (int o = 32; o; o >>= 1) v += __shfl_down(v, o, 64);
  __syncthreads();
  if ((t & 63) == 0) sh[t >> 6] = v;
  __syncthreads();
  return sh[0] + sh[1] + sh[2] + sh[3];
}

__device__ __forceinline__ float bmax256(float v, float* sh){
  int t = threadIdx.x;
  for (int o = 32; o; o >>= 1) v = fmaxf(v, __shfl_down(v, o, 64));
  __syncthreads();
  if ((t & 63) == 0) sh[t >> 6] = v;
  __syncthreads();
  return fmaxf(fmaxf(sh[0], sh[1]), fmaxf(sh[2], sh[3]));
}

__device__ __forceinline__ void gld16(const void* g, void* l){
  __builtin_amdgcn_global_load_lds(
      (const __attribute__((address_space(1))) unsigned int*)g,
      (__attribute__((address_space(3))) unsigned int*)l, 16, 0, 0);
}

// ================= fused preprocessing =================
// [0,2048):   temporal-mem max-pool -> umax/msum/wnorm/gbf (+pads)
// [2048,2560): region pass -> A_kv (row=bt*20+r), rmaxr, rmsum, ubf (+pads)
// [2560,8704): weight transpose+convert -> Wall
// [8704,9024): q = (onehot@entity_W + b) @ Wq
__global__ __launch_bounds__(256) void k_pre(
    const float* __restrict__ F, const float* __restrict__ TMm,
    const float* __restrict__ Wk, const float* __restrict__ Wv, const float* __restrict__ W1,
    unsigned short* __restrict__ Wall,
    unsigned short* __restrict__ A, float* __restrict__ rmaxr, float* __restrict__ rmsum,
    unsigned short* __restrict__ ubf,
    float* __restrict__ umax, float* __restrict__ msum, unsigned short* __restrict__ wnorm,
    unsigned short* __restrict__ gbf,
    const int* __restrict__ labels, const float* __restrict__ entW, const float* __restrict__ entB,
    const float* __restrict__ Wq, float* __restrict__ q){
  __shared__ char smem[4352];
  int bid = blockIdx.x, t = threadIdx.x;
  if (bid < 2048){
    int m = bid;
    if (m >= TM_){   // zero wnorm + gbf pad rows
      int4 zz = make_int4(0,0,0,0);
      int4* r1 = (int4*)(wnorm + (size_t)m*D_);
      int4* r2 = (int4*)(gbf + (size_t)m*D_);
      r1[t] = zz; r1[t + 256] = zz;
      r2[t] = zz; r2[t + 256] = zz;
      return;
    }
    float* sh = (float*)smem;
    const float* base = TMm + (size_t)m*T_*D_;
    float4 mx[4];
#pragma unroll
    for (int i = 0; i < 4; ++i) mx[i] = make_float4(-1e30f,-1e30f,-1e30f,-1e30f);
    for (int f = 0; f < T_; ++f){
#pragma unroll
      for (int i = 0; i < 4; ++i){
        float4 v = *(const float4*)(base + (size_t)f*D_ + i*1024 + t*4);
        mx[i].x = fmaxf(mx[i].x, v.x); mx[i].y = fmaxf(mx[i].y, v.y);
        mx[i].z = fmaxf(mx[i].z, v.z); mx[i].w = fmaxf(mx[i].w, v.w);
      }
    }
    float s = 0.f;
#pragma unroll
    for (int i = 0; i < 4; ++i){
      *(float4*)(umax + (size_t)m*D_ + i*1024 + t*4) = mx[i];
      st_bf4(gbf + (size_t)m*D_ + i*1024 + t*4, mx[i]);   // G-GEMM A operand
      s += mx[i].x*mx[i].x + mx[i].y*mx[i].y + mx[i].z*mx[i].z + mx[i].w*mx[i].w;
    }
    s = bsum256(s, sh);
    if (t == 0) msum[m] = s;
    float inv = 1.f / fmaxf(sqrtf(s), 1e-12f);
#pragma unroll
    for (int i = 0; i < 4; ++i){
      float4 u = mx[i];
      u.x *= inv; u.y *= inv; u.z *= inv; u.w *= inv;
      st_bf4(wnorm + (size_t)m*D_ + i*1024 + t*4, u);
    }
  } else if (bid < 2560){
    int bt = bid - 2048;
    if (bt >= 400){  // zero ubf pad row + two A_kv pad rows
      int4 zz = make_int4(0,0,0,0);
      int4* r1 = (int4*)(ubf + (size_t)bt*D_);
      r1[t] = zz; r1[t + 256] = zz;
      int base = 8000 + (bt - 400)*2;
#pragma unroll
      for (int k = 0; k < 2; ++k){
        if (base + k < MREG){
          int4* r2 = (int4*)(A + (size_t)(base + k)*D_);
          r2[t] = zz; r2[t + 256] = zz;
        }
      }
      return;
    }
    float* sh = (float*)smem;
    const float* fb = F + (size_t)bt*RN*D_;
    unsigned short* ab = A + (size_t)bt*RN*D_;
    float4 mx[4];
#pragma unroll
    for (int i = 0; i < 4; ++i) mx[i] = make_float4(-1e30f,-1e30f,-1e30f,-1e30f);
    float4 vn[4];
#pragma unroll
    for (int i = 0; i < 4; ++i) vn[i] = *(const float4*)(fb + i*1024 + t*4);
    for (int r = 0; r < RN; ++r){
      float4 v[4];
      float s = 0.f;
#pragma unroll
      for (int i = 0; i < 4; ++i){
        v[i] = vn[i];
        s += v[i].x*v[i].x + v[i].y*v[i].y + v[i].z*v[i].z + v[i].w*v[i].w;
      }
      if (r + 1 < RN){   // prefetch next row before the barrier-reduce
#pragma unroll
        for (int i = 0; i < 4; ++i)
          vn[i] = *(const float4*)(fb + (size_t)(r+1)*D_ + i*1024 + t*4);
      }
      s = bsum256(s, sh);
      float ri = 1.f / fmaxf(sqrtf(s), 1e-12f);
#pragma unroll
      for (int i = 0; i < 4; ++i){
        v[i].x *= ri; v[i].y *= ri; v[i].z *= ri; v[i].w *= ri;
        st_bf4(ab + (size_t)r*D_ + i*1024 + t*4, v[i]);
        mx[i].x = fmaxf(mx[i].x, v[i].x); mx[i].y = fmaxf(mx[i].y, v[i].y);
        mx[i].z = fmaxf(mx[i].z, v[i].z); mx[i].w = fmaxf(mx[i].w, v[i].w);
      }
    }
    float s2 = 0.f;
#pragma unroll
    for (int i = 0; i < 4; ++i){
      *(float4*)(rmaxr + (size_t)bt*D_ + i*1024 + t*4) = mx[i];
      s2 += mx[i].x*mx[i].x + mx[i].y*mx[i].y + mx[i].z*mx[i].z + mx[i].w*mx[i].w;
    }
    s2 = bsum256(s2, sh);
    if (t == 0) rmsum[bt] = s2;
    float inv = 1.f / fmaxf(sqrtf(s2), 1e-12f);
#pragma unroll
    for (int i = 0; i < 4; ++i){
      float4 u = mx[i];
      u.x *= inv; u.y *= inv; u.z *= inv; u.w *= inv;
      st_bf4(ubf + (size_t)bt*D_ + i*1024 + t*4, u);
    }
  } else if (bid < 8704){
    int wti = bid - 2560;
    float* tile = (float*)smem;          // [32][33]
    int kb = (wti & 127) * 32, nb = (wti >> 7) * 32;
    const float* src; int nc0;
    if (nb < 512)      { src = Wk; nc0 = nb; }
    else if (nb < 1024){ src = Wv; nc0 = nb - 512; }
    else               { src = W1; nc0 = nb - 1024; }
    int tx = t & 31, ty = t >> 5;
#pragma unroll
    for (int j = 0; j < 4; ++j){
      int k = kb + ty + j*8;
      tile[(ty + j*8)*33 + tx] = src[(size_t)k*E_ + nc0 + tx];
    }
    __syncthreads();
#pragma unroll
    for (int j = 0; j < 4; ++j){
      int n = nb + ty + j*8;
      int k = kb + tx;
      Wall[(size_t)n*D_ + k] = f2bf(tile[tx*33 + ty + j*8]);
    }
  } else {
    int bo = bid - 8704;
    float* qe = (float*)smem;
    int lab = labels[bo];
    float sel = (lab != 0) ? 1.f : 0.f;
    qe[t]       = sel * entW[(size_t)lab*E_ + t]       + entB[t];
    qe[t + 256] = sel * entW[(size_t)lab*E_ + t + 256] + entB[t + 256];
    __syncthreads();
    float a0 = 0.f, a1 = 0.f;
    for (int ep = 0; ep < E_; ++ep){
      float r = qe[ep];
      a0 += r * Wq[(size_t)ep*E_ + t];
      a1 += r * Wq[(size_t)ep*E_ + t + 256];
    }
    q[(size_t)bo*E_ + t] = a0;
    q[(size_t)bo*E_ + t + 256] = a1;
  }
}

// ---------- combined 256x256 bf16 GEMM dispatch: mega | sim | G ----------
// grid = 256 blocks exactly (one per CU): [0,192) mega 32x6, [192,208) sim 2x8,
// [208,256) G 8x6. BK=64, 8 waves, double-buffered prefetch, 1 barrier/K-tile.
__global__ __launch_bounds__(512, 1) void k_gemm3(
    const unsigned short* __restrict__ Akv, const unsigned short* __restrict__ Wall,
    const unsigned short* __restrict__ ubf, const unsigned short* __restrict__ wnorm,
    const unsigned short* __restrict__ gbf,
    float* __restrict__ C2, float* __restrict__ simc, float* __restrict__ Gc){
  __shared__ char lds[131072];   // buf c at c*65536: A[256][64] @ +0, B[256][64] @ +32768
  int bid = blockIdx.x;
  bid = (bid & 7)*32 + (bid >> 3);   // XCD swizzle (256 % 8 == 0: bijective)
  const unsigned short *A, *Bw; float* C; int nNt, ldc, mt, nt;
  if (bid < 192){       A = Akv; Bw = Wall;  C = C2;   nNt = 6; ldc = NW;   mt = bid/6;  nt = bid%6; }
  else if (bid < 208){  int s = bid - 192;
                        A = ubf; Bw = wnorm; C = simc; nNt = 8; ldc = NSIM; mt = s/8;    nt = s%8; }
  else {                int s = bid - 208;
                        A = gbf; Bw = Wall;  C = Gc;   nNt = 6; ldc = NW;   mt = s/6;    nt = s%6; }
  int tid = threadIdx.x, wid = tid >> 6, l = tid & 63;
  int wr = (wid >> 2) * 128;     // 2 waves in M
  int wc = (wid & 3) * 64;       // 4 waves in N
  int fr = l & 15, fq = l >> 4;
  const char* Ab = (const char*)A + (size_t)mt*256*(size_t)(D_*2);
  const char* Bb = (const char*)Bw + (size_t)nt*256*(size_t)(D_*2);
  f32x4 acc[8][4];
#pragma unroll
  for (int m = 0; m < 8; ++m)
#pragma unroll
    for (int n = 0; n < 4; ++n) acc[m][n] = (f32x4){0.f,0.f,0.f,0.f};

#pragma unroll
  for (int i = 0; i < 4; ++i){   // stage K-tile 0 into buf 0
    int idx = i*512 + tid;
    int row = idx >> 3, u = idx & 7;
    int ul = u ^ (row & 7);
    gld16(Ab + (size_t)row*(D_*2) + (size_t)(ul*16), lds + idx*16);
    gld16(Bb + (size_t)row*(D_*2) + (size_t)(ul*16), lds + 32768 + idx*16);
  }
  __syncthreads();

  int c = 0;
  for (int kt = 0; kt < D_/64; ++kt){
    if (kt < D_/64 - 1){
      int ktoff = (kt + 1) * 128;
      char* dA = lds + (c^1)*65536;
      char* dB = dA + 32768;
#pragma unroll
      for (int i = 0; i < 4; ++i){
        int idx = i*512 + tid;
        int row = idx >> 3, u = idx & 7;
        int ul = u ^ (row & 7);
        gld16(Ab + (size_t)row*(D_*2) + ktoff + ul*16, dA + idx*16);
        gld16(Bb + (size_t)row*(D_*2) + ktoff + ul*16, dB + idx*16);
      }
    }
    const char* LA = lds + c*65536;
    const char* LB = LA + 32768;
    bf16x8 bv[4][2];
#pragma unroll
    for (int n = 0; n < 4; ++n)
#pragma unroll
      for (int kk = 0; kk < 2; ++kk){
        int row = wc + n*16 + fr;
        int u = (kk*4 + fq) ^ (row & 7);
        bv[n][kk] = *(const bf16x8*)(LB + row*128 + u*16);
      }
    __builtin_amdgcn_s_setprio(1);
#pragma unroll
    for (int mp = 0; mp < 4; ++mp){
      bf16x8 av[2][2];
#pragma unroll
      for (int mm = 0; mm < 2; ++mm)
#pragma unroll
        for (int kk = 0; kk < 2; ++kk){
          int row = wr + (mp*2 + mm)*16 + fr;
          int u = (kk*4 + fq) ^ (row & 7);
          av[mm][kk] = *(const bf16x8*)(LA + row*128 + u*16);
        }
#pragma unroll
      for (int mm = 0; mm < 2; ++mm)
#pragma unroll
        for (int n = 0; n < 4; ++n)
#pragma unroll
          for (int kk = 0; kk < 2; ++kk)
            acc[mp*2 + mm][n] = __builtin_amdgcn_mfma_f32_16x16x32_bf16(
                av[mm][kk], bv[n][kk], acc[mp*2 + mm][n], 0, 0, 0);
    }
    __builtin_amdgcn_s_setprio(0);
    __syncthreads();
    c ^= 1;
  }
  size_t crow0 = (size_t)mt*256 + wr, ccol0 = (size_t)nt*256 + wc;
#pragma unroll
  for (int m = 0; m < 8; ++m)
#pragma unroll
    for (int n = 0; n < 4; ++n){
      size_t r0 = crow0 + m*16 + fq*4, c0 = ccol0 + n*16 + fr;
#pragma unroll
      for (int j = 0; j < 4; ++j)
        C[(r0 + j)*(size_t)ldc + c0] = acc[m][n][j];
    }
}

// ---------- prune + fp32 rescore + gather precomputed G row into C2 mem rows ----------
__global__ __launch_bounds__(256) void k_pick(const float* __restrict__ simc,
                                              const float* __restrict__ rmaxr, const float* __restrict__ rmsum,
                                              const float* __restrict__ umax, const float* __restrict__ msum,
                                              const float* __restrict__ Gc, float* __restrict__ C2){
  int bt = blockIdx.x, t = threadIdx.x;
  __shared__ float srow[1920];
  __shared__ float sh[4];
  __shared__ int cnt;
  __shared__ int cl[CAP];
  for (int m = t; m < TM_; m += 256) srow[m] = simc[(size_t)bt*NSIM + m];
  if (t == 0) cnt = 0;
  __syncthreads();
  float mx = -1e30f;
  for (int m = t; m < TM_; m += 256) mx = fmaxf(mx, srow[m]);
  mx = bmax256(mx, sh);
  float thr = mx - 2.5e-4f;
  for (int m = t; m < TM_; m += 256){
    if (srow[m] >= thr){
      int p = atomicAdd(&cnt, 1);
      if (p < CAP) cl[p] = m;
    }
  }
  __syncthreads();
  int cn = cnt < CAP ? cnt : CAP;
  float rinvv = 1.f / fmaxf(sqrtf(rmsum[bt]), 1e-12f);
  const float* a = rmaxr + (size_t)bt*D_;
  float best = -1e30f; int bestm = 0x7fffffff;
  for (int ci = 0; ci < cn; ++ci){
    int m = cl[ci];
    const float* wrow = umax + (size_t)m*D_;
    float p = 0.f;
    for (int i = t*4; i < D_; i += 1024){
      float4 av = *(const float4*)(a + i);
      float4 wv = *(const float4*)(wrow + i);
      p += av.x*wv.x + av.y*wv.y + av.z*wv.z + av.w*wv.w;
    }
    p = bsum256(p, sh);
    float sim = p * rinvv * (1.f / fmaxf(sqrtf(msum[m]), 1e-12f));
    if (sim > best || (sim == best && m < bestm)){ best = sim; bestm = m; }
  }
  // gather precomputed mem-row outputs: C2 row (MREG + bt) = Gc[bestm]
  const float4* src = (const float4*)(Gc + (size_t)bestm*NW);
  float4* dst = (float4*)(C2 + (size_t)(MREG + bt)*NW);
  if (t < 128){ dst[t] = src[t]; dst[t + 128] = src[t + 128]; dst[t + 256] = src[t + 256]; }
}

// ================= fused post-GEMM =================
// [0,160): attention per (b,h) ; [160,560): hi/lo per (b,t) ; [560,2560): z-MLP
// C2 row map: region (b,n<400) -> b*400+n ; mem (b,tt) -> MREG + b*20 + tt
__global__ __launch_bounds__(256) void k_post(const float* __restrict__ q, const float* __restrict__ c2,
                                              float* __restrict__ fpre, int* __restrict__ hi,
                                              int* __restrict__ lo, const float* __restrict__ b1,
                                              const float* __restrict__ W2, const float* __restrict__ b2,
                                              float* __restrict__ z){
  __shared__ char smem[58368];
  int bid = blockIdx.x, t = threadIdx.x;
  if (bid < 160){
    int b = bid >> 3, h = bid & 7;
    int w = t >> 6, l = t & 63;
    float* qhp = (float*)smem;               // [16][65]
    float* kb  = (float*)(smem + 4160);      // [105][65]
    float* sc  = (float*)(smem + 31460);     // [16][420]
    for (int i = t; i < O_*DH; i += 256){
      int o = i >> 6, d = i & 63;
      qhp[o*65 + d] = q[((size_t)(b*O_ + o))*E_ + h*DH + d] * 0.125f;
    }
    __syncthreads();
    for (int c = 0; c < 4; ++c){
      for (int i = t; i < 105*DH; i += 256){
        int j = i >> 6, d = i & 63;
        int n = c*105 + j;
        size_t row = n < 400 ? (size_t)b*400 + n : (size_t)MREG + b*20 + (n - 400);
        kb[j*65 + d] = c2[row*NW + h*DH + d];
      }
      __syncthreads();
      for (int i = t; i < O_*105; i += 256){
        int o = i / 105, j = i % 105;
        float acc = 0.f;
        for (int d = 0; d < DH; ++d) acc += qhp[o*65 + d] * kb[j*65 + d];
        sc[o*420 + c*105 + j] = acc;
      }
      __syncthreads();
    }
    for (int oi = 0; oi < 4; ++oi){
      int o = w + oi*4;
      float mxv = -1e30f;
      for (int n = l; n < 420; n += 64) mxv = fmaxf(mxv, sc[o*420 + n]);
      for (int of = 32; of; of >>= 1) mxv = fmaxf(mxv, __shfl_xor(mxv, of, 64));
      float sum = 0.f;
      for (int n = l; n < 420; n += 64){ float e = expf(sc[o*420 + n] - mxv); sc[o*420 + n] = e; sum += e; }
      for (int of = 32; of; of >>= 1) sum += __shfl_xor(sum, of, 64);
      float inv = 1.f / sum;
      for (int n = l; n < 420; n += 64) sc[o*420 + n] *= inv;
    }
    __syncthreads();
    float acc[4] = {0.f, 0.f, 0.f, 0.f};
    for (int c = 0; c < 4; ++c){
      for (int i = t; i < 105*DH; i += 256){
        int j = i >> 6, d = i & 63;
        int n = c*105 + j;
        size_t row = n < 400 ? (size_t)b*400 + n : (size_t)MREG + b*20 + (n - 400);
        kb[j*65 + d] = c2[row*NW + E_ + h*DH + d];
      }
      __syncthreads();
#pragma unroll
      for (int og = 0; og < 4; ++og){
        int o = og*4 + w;
        float a = 0.f;
        for (int j = 0; j < 105; ++j) a += sc[o*420 + c*105 + j] * kb[j*65 + l];
        acc[og] += a;
      }
      __syncthreads();
    }
#pragma unroll
    for (int og = 0; og < 4; ++og){
      int o = og*4 + w;
      fpre[((size_t)(b*O_ + o))*E_ + h*DH + l] = acc[og];
    }
  } else if (bid < 560){
    int bt = bid - 160;
    int b = bt / T_, tt = bt % T_;
    float* kl = (float*)smem;                // [20][513]
    float* qr = (float*)(smem + 41040);      // [16][20]
    for (int i = t; i < RN*E_; i += 256){
      int r = i >> 9, e = i & 511;
      kl[r*513 + e] = c2[((size_t)b*400 + tt*RN + r)*NW + e];
    }
    __syncthreads();
#pragma unroll
    for (int pp = 0; pp < 2; ++pp){
      int p = t + pp*256;
      if (p < O_*RN){
        int o = p / RN, r = p % RN;
        const float* qrow = q + ((size_t)(b*O_ + o))*E_;
        float acc = 0.f;
        for (int e = 0; e < E_; ++e) acc += qrow[e] * kl[r*513 + e];
        qr[o*20 + r] = acc;
      }
    }
    __syncthreads();
    if (t < O_){
      int o = t;
      float bh = qr[o*20], bl = qr[o*20]; int ih = 0, il = 0;
#pragma unroll
      for (int r = 1; r < RN; ++r){
        float v = qr[o*20 + r];
        if (v > bh){ bh = v; ih = r; }
        if (v < bl){ bl = v; il = r; }
      }
      int rowbase = b*400 + tt*RN;
      int outi = (b*O_ + o)*T_ + tt;
      hi[outi] = rowbase + ih;
      lo[outi] = rowbase + il;
    }
  } else {
    int g = (bid - 560)*4 + (t >> 6);        // region row id 0..7999
    int l = t & 63;
    const float* hrow = c2 + (size_t)g*NW + 1024;
    float acc = 0.f;
    for (int e = l; e < E_; e += 64) acc += tanhf(hrow[e] + b1[e]) * W2[e];
    for (int of = 32; of; of >>= 1) acc += __shfl_down(acc, of, 64);
    if (l == 0) z[g] = 1.f / (1.f + expf(-(acc + b2[0])));
  }
}

// ---------- out = fpre @ Wo + beta*gce (gce recomputed per block) ----------
__global__ __launch_bounds__(256) void k_outg(const float* __restrict__ fpre, const float* __restrict__ Wo,
                                              const float* __restrict__ z, const int* __restrict__ hi,
                                              const int* __restrict__ lo, const int* __restrict__ labels,
                                              float* __restrict__ out){
  int bo = blockIdx.x, t = threadIdx.x;
  __shared__ float rowv[E_];
  __shared__ float vb[B_];
  __shared__ int cb[B_];
  __shared__ float gsh;
  rowv[t] = fpre[(size_t)bo*E_ + t];
  rowv[t + 256] = fpre[(size_t)bo*E_ + t + 256];
  if (t < B_){ vb[t] = 0.f; cb[t] = 0; }
  __syncthreads();
  for (int p = t; p < B_*O_; p += 256){
    int b = p / O_;
    if (labels[p] != 0){
      float acc = 0.f;
      for (int tt = 0; tt < T_; ++tt){
        float shi = z[hi[p*T_ + tt]];
        float slo = z[lo[p*T_ + tt]];
        acc += (1.f - __powf(shi + 1e-7f, 0.7f)) / 0.7f;
        acc += (1.f - __powf(1.f - slo + 1e-7f, 0.7f)) / 0.7f;
      }
      atomicAdd(&vb[b], acc / (float)T_);
      atomicAdd(&cb[b], 1);
    }
  }
  __syncthreads();
  if (t == 0){
    float g = 0.f;
    for (int b = 0; b < B_; ++b) g += vb[b] / fmaxf((float)cb[b], 1.f);
    gsh = 0.5f * (g / (float)B_);
  }
  __syncthreads();
  float g = gsh;
  float a0 = 0.f, a1 = 0.f;
  for (int ep = 0; ep < E_; ++ep){
    float r = rowv[ep];
    a0 += r * Wo[(size_t)ep*E_ + t];
    a1 += r * Wo[(size_t)ep*E_ + t + 256];
  }
  out[(size_t)bo*E_ + t] = a0 + g;
  out[(size_t)bo*E_ + t + 256] = a1 + g;
}

extern "C" void kernel_launch(void* const* d_in, const int* in_sizes, int n_in,
                              void* d_out, int out_size, void* d_ws, size_t ws_size,
                              hipStream_t stream) {
  (void)in_sizes; (void)n_in; (void)out_size; (void)ws_size;
  const float* F    = (const float*)d_in[0];
  const int*   labels = (const int*)d_in[1];
  const float* TMm  = (const float*)d_in[2];
  const float* entW = (const float*)d_in[3];
  const float* entB = (const float*)d_in[4];
  const float* Wq   = (const float*)d_in[5];
  const float* Wk   = (const float*)d_in[6];
  const float* Wv   = (const float*)d_in[7];
  const float* Wo   = (const float*)d_in[8];
  const float* W1   = (const float*)d_in[9];
  const float* b1   = (const float*)d_in[10];
  const float* W2   = (const float*)d_in[11];
  const float* b2   = (const float*)d_in[12];
  float* out = (float*)d_out;

  size_t off = 0;
  char* wsb = (char*)d_ws;
  auto alloc = [&](size_t bytes) -> char* {
    char* p = wsb + off; off += (bytes + 255) & ~(size_t)255; return p;
  };
  unsigned short* A_kv = (unsigned short*)alloc((size_t)MREG * D_ * 2);
  unsigned short* Wall = (unsigned short*)alloc((size_t)NW * D_ * 2);
  float* umax          = (float*)alloc((size_t)TM_ * D_ * 4);
  unsigned short* gbf  = (unsigned short*)alloc((size_t)NSIM * D_ * 2);
  unsigned short* wnorm= (unsigned short*)alloc((size_t)NSIM * D_ * 2);
  unsigned short* ubf  = (unsigned short*)alloc((size_t)MSIM * D_ * 2);
  float* rmaxr = (float*)alloc((size_t)400 * D_ * 4);
  float* simc  = (float*)alloc((size_t)MSIM * NSIM * 4);
  float* Gc    = (float*)alloc((size_t)NSIM * NW * 4);
  float* C2    = (float*)alloc((size_t)(MREG + 512) * NW * 4);
  float* qbuf  = (float*)alloc((size_t)B_ * O_ * E_ * 4);
  float* fpre  = (float*)alloc((size_t)B_ * O_ * E_ * 4);
  float* rmsum = (float*)alloc(400 * 4);
  float* msum  = (float*)alloc(TM_ * 4);
  int*   hib   = (int*)alloc(6400 * 4);
  int*   lob   = (int*)alloc(6400 * 4);
  float* zbuf  = (float*)alloc(8000 * 4);

  // fused preprocessing: mempool+gbf | region | weight-transpose | q
  k_pre<<<9024, 256, 0, stream>>>(F, TMm, Wk, Wv, W1, Wall, A_kv, rmaxr, rmsum, ubf,
                                  umax, msum, wnorm, gbf, labels, entW, entB, Wq, qbuf);
  // combined GEMM: mega(region) | sim | G — 256 blocks = 1/CU, one round
  k_gemm3<<<256, 512, 0, stream>>>(A_kv, Wall, ubf, wnorm, gbf, C2, simc, Gc);
  // prune + fp32 rescore + gather G row into C2 mem rows
  k_pick<<<400, 256, 0, stream>>>(simc, rmaxr, rmsum, umax, msum, Gc, C2);
  // fused post: attention | hi/lo | z-MLP
  k_post<<<2560, 256, 0, stream>>>(qbuf, C2, fpre, hib, lob, b1, W2, b2, zbuf);
  // out = fpre @ Wo + beta*gce
  k_outg<<<B_*O_, 256, 0, stream>>>(fpre, Wo, zbuf, hib, lob, labels, out);
}